// Round 3
// baseline (2053.654 us; speedup 1.0000x reference)
//
#include <hip/hip_runtime.h>
#include <hip/hip_bf16.h>

#define BN    4112            // sequence length
#define BB    2               // batch
#define HH    8               // heads
#define NIMG_ 4096
#define NKT   4048            // BN - 64 (main keys)
#define MROWS 8224            // BB*BN

typedef __hip_bfloat16 bf16;

__device__ __forceinline__ float blo(unsigned u) { return __uint_as_float(u << 16); }
__device__ __forceinline__ float bhi(unsigned u) { return __uint_as_float(u & 0xffff0000u); }
__device__ __forceinline__ unsigned short f2bs(float x) { return __bfloat16_as_ushort(__float2bfloat16(x)); }

// ---------------- GEMM: out[row][o] = sum_d A[row][d]*W[o][d] + bias[o] ----------------
// W, bias fp32. OMODE: 0 = head-split fp32, 1 = head-split bf16, 2 = row-major fp32.
template<bool ABF16, bool ROPE, int OMODE>
__global__ __launch_bounds__(256)
void gemm256(const void* __restrict__ Av, const float* __restrict__ W,
             const float* __restrict__ bias, void* __restrict__ outv,
             const float* __restrict__ fimg, const float* __restrict__ ftxt)
{
    __shared__ float As[64][68];   // [k][row]; 68*4=272 B rows keep float4 alignment
    __shared__ float Bs[64][68];   // [k][col]
    const int t  = threadIdx.x;
    const int tx = t & 15, ty = t >> 4;
    const int m0 = blockIdx.x * 64, n0 = blockIdx.y * 64;
    const bf16*  Ab = (const bf16*)Av;
    const float* Af = (const float*)Av;

    float acc[4][4] = {};
    for (int k0 = 0; k0 < 256; k0 += 64) {
        #pragma unroll
        for (int i = 0; i < 16; i++) {
            int idx = t + 256 * i;
            int r = idx >> 6, c = idx & 63;
            int row = m0 + r;
            float av = 0.f;
            if (row < MROWS)
                av = ABF16 ? __bfloat162float(Ab[(size_t)row * 256 + k0 + c])
                           : Af[(size_t)row * 256 + k0 + c];
            As[c][r] = av;
            Bs[c][r] = W[(size_t)(n0 + r) * 256 + k0 + c];
        }
        __syncthreads();
        #pragma unroll
        for (int kk = 0; kk < 64; kk++) {
            float4 a = *(const float4*)&As[kk][ty * 4];
            float4 b = *(const float4*)&Bs[kk][tx * 4];
            acc[0][0] += a.x*b.x; acc[0][1] += a.x*b.y; acc[0][2] += a.x*b.z; acc[0][3] += a.x*b.w;
            acc[1][0] += a.y*b.x; acc[1][1] += a.y*b.y; acc[1][2] += a.y*b.z; acc[1][3] += a.y*b.w;
            acc[2][0] += a.z*b.x; acc[2][1] += a.z*b.y; acc[2][2] += a.z*b.z; acc[2][3] += a.z*b.w;
            acc[3][0] += a.w*b.x; acc[3][1] += a.w*b.y; acc[3][2] += a.w*b.z; acc[3][3] += a.w*b.w;
        }
        __syncthreads();
    }

    const int c0 = n0 + tx * 4;
    float b0 = bias[c0], b1 = bias[c0+1], b2 = bias[c0+2], b3 = bias[c0+3];

    #pragma unroll
    for (int i = 0; i < 4; i++) {
        int row = m0 + ty * 4 + i;
        if (row >= MROWS) continue;
        float o0 = acc[i][0] + b0, o1 = acc[i][1] + b1;
        float o2 = acc[i][2] + b2, o3 = acc[i][3] + b3;
        int b = row / BN;
        int n = row - b * BN;
        if (ROPE) {
            int j0 = (c0 & 31) >> 1;   // complex-pair index within head (c0 % 4 == 0)
            const float* f = (n < NIMG_) ? (fimg + ((size_t)n * 16 + j0) * 2)
                                         : (ftxt + ((size_t)(n - NIMG_) * 16 + j0) * 2);
            float cc0 = f[0], ss0 = f[1];
            float cc1 = f[2], ss1 = f[3];
            float r0 = o0 * cc0 - o1 * ss0, i0 = o0 * ss0 + o1 * cc0;
            float r1 = o2 * cc1 - o3 * ss1, i1 = o2 * ss1 + o3 * cc1;
            o0 = r0; o1 = i0; o2 = r1; o3 = i1;
        }
        if (OMODE == 0) {
            int h = c0 >> 5, hd = c0 & 31;
            float* op = (float*)outv + ((size_t)((b * HH + h) * BN + n)) * 32 + hd;
            float4 w = {o0, o1, o2, o3};
            *(float4*)op = w;
        } else if (OMODE == 1) {
            int h = c0 >> 5, hd = c0 & 31;
            bf16* op = (bf16*)outv + ((size_t)((b * HH + h) * BN + n)) * 32 + hd;
            ushort4 w = { f2bs(o0), f2bs(o1), f2bs(o2), f2bs(o3) };
            *(ushort4*)op = w;
        } else {
            float* op = (float*)outv + (size_t)row * 256 + c0;
            float4 w = {o0, o1, o2, o3};
            *(float4*)op = w;
        }
    }
}

// ------------- fused attention: main 4048-key softmax + separate 64-key mem softmax -------------
// one wave per block; lane t owns query q = blockIdx.x*64 + t; bh = b*8+h
__global__ __launch_bounds__(64)
void attn_fused(const float* __restrict__ Qr, const bf16* __restrict__ Kr,
                const bf16* __restrict__ Vr, bf16* __restrict__ AO)
{
    const int t  = threadIdx.x;
    const int bh = blockIdx.y;
    const int q  = blockIdx.x * 64 + t;
    const bool valid = q < BN;
    const int qc = valid ? q : BN - 1;
    const float scale = 0.17677669529663687f;  // 1/sqrt(32)

    float qv[32];
    {
        const float4* qp = (const float4*)(Qr + ((size_t)bh * BN + qc) * 32);
        #pragma unroll
        for (int i = 0; i < 8; i++) {
            float4 a = qp[i];
            qv[i*4+0] = a.x * scale; qv[i*4+1] = a.y * scale;
            qv[i*4+2] = a.z * scale; qv[i*4+3] = a.w * scale;
        }
    }

    __shared__ uint4 Ksm[256];   // 64 keys x 32 bf16 = 4 KB
    __shared__ uint4 Vsm[256];

    float o[32] = {};
    float L = 0.f;

    for (int kb = 0; kb < NKT; kb += 64) {
        const uint4* Kg = (const uint4*)(Kr + ((size_t)bh * BN + kb) * 32);
        const uint4* Vg = (const uint4*)(Vr + ((size_t)bh * BN + kb) * 32);
        #pragma unroll
        for (int i = 0; i < 4; i++) { Ksm[t + 64*i] = Kg[t + 64*i]; Vsm[t + 64*i] = Vg[t + 64*i]; }
        __syncthreads();

        for (int kk = 0; kk < 64; kk++) {
            const uint4* kp = &Ksm[kk * 4];
            float s = 0.f;
            #pragma unroll
            for (int c = 0; c < 4; c++) {
                uint4 u = kp[c];
                s += qv[c*8+0]*blo(u.x) + qv[c*8+1]*bhi(u.x)
                   + qv[c*8+2]*blo(u.y) + qv[c*8+3]*bhi(u.y)
                   + qv[c*8+4]*blo(u.z) + qv[c*8+5]*bhi(u.z)
                   + qv[c*8+6]*blo(u.w) + qv[c*8+7]*bhi(u.w);
            }
            float p = __expf(s);
            L += p;
            const uint4* vp = &Vsm[kk * 4];
            #pragma unroll
            for (int c = 0; c < 4; c++) {
                uint4 u = vp[c];
                o[c*8+0] += p*blo(u.x); o[c*8+1] += p*bhi(u.x);
                o[c*8+2] += p*blo(u.y); o[c*8+3] += p*bhi(u.y);
                o[c*8+4] += p*blo(u.z); o[c*8+5] += p*bhi(u.z);
                o[c*8+6] += p*blo(u.w); o[c*8+7] += p*bhi(u.w);
            }
        }
        __syncthreads();
    }

    float invL = 1.f / L;
    #pragma unroll
    for (int d = 0; d < 32; d++) o[d] *= invL;

    // ---- mem segment: last 64 keys, separate softmax ----
    {
        const uint4* Kg = (const uint4*)(Kr + ((size_t)bh * BN + NKT) * 32);
        const uint4* Vg = (const uint4*)(Vr + ((size_t)bh * BN + NKT) * 32);
        #pragma unroll
        for (int i = 0; i < 4; i++) { Ksm[t + 64*i] = Kg[t + 64*i]; Vsm[t + 64*i] = Vg[t + 64*i]; }
    }
    __syncthreads();

    float o2[32] = {};
    float l2 = 0.f;
    for (int kk = 0; kk < 64; kk++) {
        const uint4* kp = &Ksm[kk * 4];
        float s = 0.f;
        #pragma unroll
        for (int c = 0; c < 4; c++) {
            uint4 u = kp[c];
            s += qv[c*8+0]*blo(u.x) + qv[c*8+1]*bhi(u.x)
               + qv[c*8+2]*blo(u.y) + qv[c*8+3]*bhi(u.y)
               + qv[c*8+4]*blo(u.z) + qv[c*8+5]*bhi(u.z)
               + qv[c*8+6]*blo(u.w) + qv[c*8+7]*bhi(u.w);
        }
        float p = __expf(s);
        l2 += p;
        const uint4* vp = &Vsm[kk * 4];
        #pragma unroll
        for (int c = 0; c < 4; c++) {
            uint4 u = vp[c];
            o2[c*8+0] += p*blo(u.x); o2[c*8+1] += p*bhi(u.x);
            o2[c*8+2] += p*blo(u.y); o2[c*8+3] += p*bhi(u.y);
            o2[c*8+4] += p*blo(u.z); o2[c*8+5] += p*bhi(u.z);
            o2[c*8+6] += p*blo(u.w); o2[c*8+7] += p*bhi(u.w);
        }
    }
    float inv2 = 1.f / l2;

    if (valid) {
        int b = bh >> 3, h = bh & 7;
        ushort4* op = (ushort4*)(AO + ((size_t)b * BN + q) * 256 + h * 32);
        #pragma unroll
        for (int c = 0; c < 8; c++) {
            ushort4 w = { f2bs(o[c*4+0] + o2[c*4+0]*inv2),
                          f2bs(o[c*4+1] + o2[c*4+1]*inv2),
                          f2bs(o[c*4+2] + o2[c*4+2]*inv2),
                          f2bs(o[c*4+3] + o2[c*4+3]*inv2) };
            op[c] = w;
        }
    }
}

extern "C" void kernel_launch(void* const* d_in, const int* in_sizes, int n_in,
                              void* d_out, int out_size, void* d_ws, size_t ws_size,
                              hipStream_t stream)
{
    (void)in_sizes; (void)n_in; (void)out_size; (void)ws_size;
    const float* q    = (const float*)d_in[0];
    const float* k    = (const float*)d_in[1];
    const float* v    = (const float*)d_in[2];
    const float* fimg = (const float*)d_in[3];
    const float* ftxt = (const float*)d_in[4];
    const float* Wq   = (const float*)d_in[5];
    const float* bq   = (const float*)d_in[6];
    const float* Wk   = (const float*)d_in[7];
    const float* bk   = (const float*)d_in[8];
    const float* Wv   = (const float*)d_in[9];
    const float* bv   = (const float*)d_in[10];
    const float* Wo   = (const float*)d_in[11];
    const float* bo   = (const float*)d_in[12];
    // d_in[13] = num_k_exclude_rope = 64 (compiled in)

    // workspace layout (bytes, 256-aligned): total 21,053,440 B (~20.1 MB)
    char* w = (char*)d_ws;
    float* Qr = (float*)(w);                  // [16][BN][32] fp32 : 8,421,376 B
    bf16*  Kr = (bf16*)(w + 8421376);         // [16][BN][32] bf16 : 4,210,688 B
    bf16*  Vr = (bf16*)(w + 12632064);        // [16][BN][32] bf16 : 4,210,688 B
    bf16*  AO = (bf16*)(w + 16842752);        // [BB][BN][256] bf16: 4,210,688 B

    dim3 gg(129, 4);
    gemm256<false, true,  0><<<gg, 256, 0, stream>>>(q,  Wq, bq, Qr,    fimg, ftxt);
    gemm256<false, true,  1><<<gg, 256, 0, stream>>>(k,  Wk, bk, Kr,    fimg, ftxt);
    gemm256<false, false, 1><<<gg, 256, 0, stream>>>(v,  Wv, bv, Vr,    fimg, ftxt);
    attn_fused<<<dim3(65, 16), 64, 0, stream>>>(Qr, Kr, Vr, AO);
    gemm256<true,  false, 2><<<gg, 256, 0, stream>>>(AO, Wo, bo, d_out, fimg, ftxt);
}

// Round 4
// 343.866 us; speedup vs baseline: 5.9723x; 5.9723x over previous
//
#include <hip/hip_runtime.h>
#include <hip/hip_bf16.h>

#define BN    4112            // sequence length
#define BB    2               // batch
#define HH    8               // heads
#define NIMG_ 4096
#define NKT   4048            // BN - 64 (main keys)
#define MROWS 8224            // BB*BN
#define SCALE 0.17677669529663687f   // 1/sqrt(32)

typedef __hip_bfloat16 bf16;
typedef __attribute__((ext_vector_type(8))) short short8;   // 8 bf16 (4 VGPRs)
typedef __attribute__((ext_vector_type(4))) short short4v;  // 4 bf16 (8 B)
typedef __attribute__((ext_vector_type(4))) float f32x4;

__device__ __forceinline__ unsigned short f2bs(float x) { return __bfloat16_as_ushort(__float2bfloat16(x)); }

// ---------------- GEMM: out[row][o] = sum_d A[row][d]*W[o][d] + bias[o] ----------------
// A fp32 [MROWS][256] (or bf16 if ABF16). OMODE: 1 = head-split bf16 [bh][n][32],
// 2 = row-major fp32, 3 = head-split bf16 scaled by SCALE (Q), 4 = transposed head-split
// bf16 [bh][hd][n] (V).
template<bool ABF16, bool ROPE, int OMODE>
__global__ __launch_bounds__(256)
void gemm256(const void* __restrict__ Av, const float* __restrict__ W,
             const float* __restrict__ bias, void* __restrict__ outv,
             const float* __restrict__ fimg, const float* __restrict__ ftxt)
{
    __shared__ float As[64][68];
    __shared__ float Bs[64][68];
    const int t  = threadIdx.x;
    const int tx = t & 15, ty = t >> 4;
    const int m0 = blockIdx.x * 64, n0 = blockIdx.y * 64;
    const bf16*  Ab = (const bf16*)Av;
    const float* Af = (const float*)Av;

    float acc[4][4] = {};
    for (int k0 = 0; k0 < 256; k0 += 64) {
        #pragma unroll
        for (int i = 0; i < 16; i++) {
            int idx = t + 256 * i;
            int r = idx >> 6, c = idx & 63;
            int row = m0 + r;
            float av = 0.f;
            if (row < MROWS)
                av = ABF16 ? __bfloat162float(Ab[(size_t)row * 256 + k0 + c])
                           : Af[(size_t)row * 256 + k0 + c];
            As[c][r] = av;
            Bs[c][r] = W[(size_t)(n0 + r) * 256 + k0 + c];
        }
        __syncthreads();
        #pragma unroll
        for (int kk = 0; kk < 64; kk++) {
            float4 a = *(const float4*)&As[kk][ty * 4];
            float4 b = *(const float4*)&Bs[kk][tx * 4];
            acc[0][0] += a.x*b.x; acc[0][1] += a.x*b.y; acc[0][2] += a.x*b.z; acc[0][3] += a.x*b.w;
            acc[1][0] += a.y*b.x; acc[1][1] += a.y*b.y; acc[1][2] += a.y*b.z; acc[1][3] += a.y*b.w;
            acc[2][0] += a.z*b.x; acc[2][1] += a.z*b.y; acc[2][2] += a.z*b.z; acc[2][3] += a.z*b.w;
            acc[3][0] += a.w*b.x; acc[3][1] += a.w*b.y; acc[3][2] += a.w*b.z; acc[3][3] += a.w*b.w;
        }
        __syncthreads();
    }

    const int c0 = n0 + tx * 4;
    float b0 = bias[c0], b1 = bias[c0+1], b2 = bias[c0+2], b3 = bias[c0+3];

    #pragma unroll
    for (int i = 0; i < 4; i++) {
        int row = m0 + ty * 4 + i;
        if (row >= MROWS) continue;
        float o0 = acc[i][0] + b0, o1 = acc[i][1] + b1;
        float o2 = acc[i][2] + b2, o3 = acc[i][3] + b3;
        int b = row / BN;
        int n = row - b * BN;
        if (ROPE) {
            int j0 = (c0 & 31) >> 1;
            const float* f = (n < NIMG_) ? (fimg + ((size_t)n * 16 + j0) * 2)
                                         : (ftxt + ((size_t)(n - NIMG_) * 16 + j0) * 2);
            float cc0 = f[0], ss0 = f[1];
            float cc1 = f[2], ss1 = f[3];
            float r0 = o0 * cc0 - o1 * ss0, i0 = o0 * ss0 + o1 * cc0;
            float r1 = o2 * cc1 - o3 * ss1, i1 = o2 * ss1 + o3 * cc1;
            o0 = r0; o1 = i0; o2 = r1; o3 = i1;
        }
        int h = (c0 >> 5) & 7, hd = c0 & 31;
        if (OMODE == 1) {
            bf16* op = (bf16*)outv + ((size_t)((b * HH + h) * BN + n)) * 32 + hd;
            ushort4 w = { f2bs(o0), f2bs(o1), f2bs(o2), f2bs(o3) };
            *(ushort4*)op = w;
        } else if (OMODE == 2) {
            float* op = (float*)outv + (size_t)row * 256 + c0;
            float4 w = {o0, o1, o2, o3};
            *(float4*)op = w;
        } else if (OMODE == 3) {
            bf16* op = (bf16*)outv + ((size_t)((b * HH + h) * BN + n)) * 32 + hd;
            ushort4 w = { f2bs(o0*SCALE), f2bs(o1*SCALE), f2bs(o2*SCALE), f2bs(o3*SCALE) };
            *(ushort4*)op = w;
        } else {  // OMODE 4: V transposed [bh][hd][n]
            unsigned short* op = (unsigned short*)outv + ((size_t)(b * HH + h) * 32 + hd) * BN + n;
            op[0]            = f2bs(o0);
            op[(size_t)BN]   = f2bs(o1);
            op[(size_t)2*BN] = f2bs(o2);
            op[(size_t)3*BN] = f2bs(o3);
        }
    }
}

// ---------------- MFMA flash attention ----------------
// block = 256 thr (4 waves), each wave owns 16 queries. S^T = K*Q^T (C-layout: col=lane&15=q,
// row=quad*4+reg=key). P^T round-trips through wave-private LDS to become the PV B-operand.
// O^T = V^T * P^T accumulated in C-layout (col=q, row=hd). Main 4048-key softmax (oA,LA) +
// separate 64-key mem softmax (oB,LB), no-max exp (logits ~ +-0.7).
__global__ __launch_bounds__(256)
void attn_mfma(const short* __restrict__ Qr, const short* __restrict__ Kr,
               const short* __restrict__ Vt, float* __restrict__ AO)
{
    __shared__ __align__(16) short Ks[64][40];      // [key][d]   stride 40 -> 2-way banks (free)
    __shared__ __align__(16) short Vs[32][88];      // V^T [hd][key] stride 88 -> 2-way
    __shared__ __align__(16) short Ps[4][16][88];   // per-wave P [q][key] stride 88

    const int t    = threadIdx.x;
    const int wave = t >> 6;
    const int lane = t & 63;
    const int q16  = lane & 15;     // = MFMA lane&15 index (query col / hd row)
    const int quad = lane >> 4;
    const int bh   = blockIdx.y;
    const int q    = blockIdx.x * 64 + wave * 16 + q16;
    const int qc   = (q < BN) ? q : (BN - 1);

    // persistent Q B-fragment: B[k=d][n=q], lane holds q=lane&15, d=quad*8+j
    const short8 qf = *(const short8*)(Qr + ((size_t)bh * BN + qc) * 32 + quad * 8);

    f32x4 oA0 = {0.f,0.f,0.f,0.f}, oA1 = {0.f,0.f,0.f,0.f};
    f32x4 oB0 = {0.f,0.f,0.f,0.f}, oB1 = {0.f,0.f,0.f,0.f};
    float LA = 0.f, LB = 0.f;

    const int kr = t >> 2, kc = t & 3;   // K staging: 64 rows x 4 chunks
    const int vr = t >> 3, vc = t & 7;   // V staging: 32 rows x 8 chunks
    const short* Kg = Kr + (size_t)bh * BN * 32;
    const short* Vg = Vt + (size_t)bh * 32 * BN;

    for (int it = 0; it < 65; ++it) {
        const int  kb  = (it < 64) ? it * 64 : NKT;   // tile 63 is partial (16 keys), 64 = mem
        const int  nk  = (it == 63) ? 16 : 64;
        const bool mem = (it == 64);

        *(uint4*)&Ks[kr][kc * 8] = *(const uint4*)(Kg + (size_t)(kb + kr) * 32 + kc * 8);
        *(uint4*)&Vs[vr][vc * 8] = *(const uint4*)(Vg + (size_t)vr * BN + kb + vc * 8);
        __syncthreads();

        // ---- S^T = K * Q^T : 4 key m-tiles ----
        f32x4 s[4];
        #pragma unroll
        for (int mt = 0; mt < 4; ++mt) {
            const short8 kf = *(const short8*)&Ks[mt * 16 + q16][quad * 8];
            f32x4 z = {0.f,0.f,0.f,0.f};
            s[mt] = __builtin_amdgcn_mfma_f32_16x16x32_bf16(kf, qf, z, 0, 0, 0);
        }

        // ---- p = exp(s), mask tail, pack bf16, L += rounded p ----
        float lsum = 0.f;
        #pragma unroll
        for (int mt = 0; mt < 4; ++mt) {
            short4v pk;
            #pragma unroll
            for (int r = 0; r < 4; ++r) {
                int key = mt * 16 + quad * 4 + r;
                float p = __expf(s[mt][r]);
                unsigned short pb = (key < nk) ? f2bs(p) : (unsigned short)0;
                pk[r] = (short)pb;
                lsum += __uint_as_float(((unsigned)pb) << 16);  // sum the rounded value
            }
            *(short4v*)&Ps[wave][q16][mt * 16 + quad * 4] = pk;
        }

        // ---- O^T += V^T * P^T ----
        const short8 p0  = *(const short8*)&Ps[wave][q16][quad * 8];        // keys 0-31
        const short8 p1  = *(const short8*)&Ps[wave][q16][32 + quad * 8];   // keys 32-63
        const short8 v00 = *(const short8*)&Vs[q16][quad * 8];              // hd 0-15, k 0-31
        const short8 v01 = *(const short8*)&Vs[q16][32 + quad * 8];
        const short8 v10 = *(const short8*)&Vs[16 + q16][quad * 8];         // hd 16-31
        const short8 v11 = *(const short8*)&Vs[16 + q16][32 + quad * 8];
        if (!mem) {
            LA += lsum;
            oA0 = __builtin_amdgcn_mfma_f32_16x16x32_bf16(v00, p0, oA0, 0, 0, 0);
            oA0 = __builtin_amdgcn_mfma_f32_16x16x32_bf16(v01, p1, oA0, 0, 0, 0);
            oA1 = __builtin_amdgcn_mfma_f32_16x16x32_bf16(v10, p0, oA1, 0, 0, 0);
            oA1 = __builtin_amdgcn_mfma_f32_16x16x32_bf16(v11, p1, oA1, 0, 0, 0);
        } else {
            LB += lsum;
            oB0 = __builtin_amdgcn_mfma_f32_16x16x32_bf16(v00, p0, oB0, 0, 0, 0);
            oB0 = __builtin_amdgcn_mfma_f32_16x16x32_bf16(v01, p1, oB0, 0, 0, 0);
            oB1 = __builtin_amdgcn_mfma_f32_16x16x32_bf16(v10, p0, oB1, 0, 0, 0);
            oB1 = __builtin_amdgcn_mfma_f32_16x16x32_bf16(v11, p1, oB1, 0, 0, 0);
        }
        __syncthreads();
    }

    // reduce L across the 4 quads (lanes sharing lane&15)
    LA += __shfl_xor(LA, 16); LA += __shfl_xor(LA, 32);
    LB += __shfl_xor(LB, 16); LB += __shfl_xor(LB, 32);

    if (q < BN) {
        const float iA = 1.f / LA, iB = 1.f / LB;
        const int b = bh >> 3, h = bh & 7;
        float* ap = AO + ((size_t)b * BN + q) * 256 + h * 32;
        f32x4 w0, w1;
        #pragma unroll
        for (int r = 0; r < 4; ++r) {
            w0[r] = oA0[r] * iA + oB0[r] * iB;   // hd = quad*4+r
            w1[r] = oA1[r] * iA + oB1[r] * iB;   // hd = 16+quad*4+r
        }
        *(f32x4*)(ap + quad * 4)      = w0;
        *(f32x4*)(ap + 16 + quad * 4) = w1;
    }
}

extern "C" void kernel_launch(void* const* d_in, const int* in_sizes, int n_in,
                              void* d_out, int out_size, void* d_ws, size_t ws_size,
                              hipStream_t stream)
{
    (void)in_sizes; (void)n_in; (void)out_size; (void)ws_size;
    const float* q    = (const float*)d_in[0];
    const float* k    = (const float*)d_in[1];
    const float* v    = (const float*)d_in[2];
    const float* fimg = (const float*)d_in[3];
    const float* ftxt = (const float*)d_in[4];
    const float* Wq   = (const float*)d_in[5];
    const float* bq   = (const float*)d_in[6];
    const float* Wk   = (const float*)d_in[7];
    const float* bk   = (const float*)d_in[8];
    const float* Wv   = (const float*)d_in[9];
    const float* bv   = (const float*)d_in[10];
    const float* Wo   = (const float*)d_in[11];
    const float* bo   = (const float*)d_in[12];
    // d_in[13] = num_k_exclude_rope = 64 (compiled in)

    // workspace: Qr/Kr bf16 [16][BN][32]; Vt bf16 [16][32][BN]; AO fp32 [BB][BN][256]
    // 4,210,688 *3 + 8,421,376 = 21,053,440 B (~20.1 MB)
    char* w = (char*)d_ws;
    short* Qr = (short*)(w);
    short* Kr = (short*)(w + 4210688);
    short* Vt = (short*)(w + 8421376);
    float* AO = (float*)(w + 12632064);

    dim3 gg(129, 4);
    gemm256<false, true,  3><<<gg, 256, 0, stream>>>(q,  Wq, bq, Qr,    fimg, ftxt);
    gemm256<false, true,  1><<<gg, 256, 0, stream>>>(k,  Wk, bk, Kr,    fimg, ftxt);
    gemm256<false, false, 4><<<gg, 256, 0, stream>>>(v,  Wv, bv, Vt,    fimg, ftxt);
    attn_mfma<<<dim3(65, 16), 256, 0, stream>>>(Qr, Kr, Vt, AO);
    gemm256<false, false, 2><<<gg, 256, 0, stream>>>(AO, Wo, bo, d_out, fimg, ftxt);
}

// Round 5
// 253.864 us; speedup vs baseline: 8.0896x; 1.3545x over previous
//
#include <hip/hip_runtime.h>
#include <hip/hip_bf16.h>

#define BN    4112            // sequence length
#define BNP   4160            // padded row stride for V^T (keeps all staging reads in-bounds)
#define BB    2
#define HH    8
#define NIMG_ 4096
#define NKT   4048            // BN - 64 (main keys)
#define MROWS 8224            // BB*BN
// (1/sqrt(32)) * log2(e): folded into Q so attention uses raw v_exp_f32 (2^x)
#define QSCALE 0.25505402f

typedef __attribute__((ext_vector_type(8))) short short8;   // 8 bf16 (4 VGPRs)
typedef __attribute__((ext_vector_type(4))) float f32x4;

__device__ __forceinline__ unsigned short f2bs(float x) { return __bfloat16_as_ushort(__float2bfloat16(x)); }
__device__ __forceinline__ unsigned pkbf(float a, float b) {
    __hip_bfloat162 h = __float22bfloat162_rn(make_float2(a, b));   // v_cvt_pk_bf16_f32
    unsigned u; __builtin_memcpy(&u, &h, 4); return u;
}
__device__ __forceinline__ float fexp2(float x) {
#if __has_builtin(__builtin_amdgcn_exp2f)
    return __builtin_amdgcn_exp2f(x);
#else
    return exp2f(x);
#endif
}

// ---------------- MFMA GEMM: out[n][f] = sum_d A[n][d]*W[f][d] + bias[f] ----------------
// MFMA roles: A-operand = W features (wave owns 16), B-operand = data rows (block owns 64).
// C-layout: col = data row (lane&15), rows = 4 CONSECUTIVE features (quad*4+r) -> RoPE is
// lane-local and stores vectorize. OMODE: 1 = head-split bf16 [bh][n][32], 2 = row-major fp32,
// 3 = head-split bf16 pre-scaled by QSCALE, 4 = transposed head-split bf16 [bh][hd][n] (V).
template<bool ROPE, int OMODE>
__global__ __launch_bounds__(256)
void gemm_mfma(const float* __restrict__ A, const float* __restrict__ W,
               const float* __restrict__ bias, void* __restrict__ outv,
               const float* __restrict__ fimg, const float* __restrict__ ftxt)
{
    __shared__ __align__(16) short Ws[64][88];   // [feature][k]  176B rows: 16B-aligned, 2-way banks
    __shared__ __align__(16) short Ds[64][88];   // [datarow][k]
    const int t    = threadIdx.x;
    const int wave = t >> 6, lane = t & 63, q16 = lane & 15, quad = lane >> 4;
    const int m0 = blockIdx.x * 64;      // data rows
    const int f0 = blockIdx.y * 64;      // features
    const int sr = t >> 2, sc = (t & 3) * 16;
    const int arow = m0 + sr;
    const bool aval = arow < MROWS;
    const float* wp = W + (size_t)(f0 + sr) * 256 + sc;
    const float* ap = A + (size_t)(aval ? arow : 0) * 256 + sc;

    f32x4 acc[4] = {{0,0,0,0},{0,0,0,0},{0,0,0,0},{0,0,0,0}};

    for (int k0 = 0; k0 < 256; k0 += 64) {
        float4 w0 = *(const float4*)(wp);     float4 w1 = *(const float4*)(wp + 4);
        float4 w2 = *(const float4*)(wp + 8); float4 w3 = *(const float4*)(wp + 12);
        float4 a0 = {0,0,0,0}, a1 = {0,0,0,0}, a2 = {0,0,0,0}, a3 = {0,0,0,0};
        if (aval) {
            a0 = *(const float4*)(ap);     a1 = *(const float4*)(ap + 4);
            a2 = *(const float4*)(ap + 8); a3 = *(const float4*)(ap + 12);
        }
        wp += 64; ap += 64;
        *(uint4*)&Ws[sr][sc]     = uint4{pkbf(w0.x,w0.y), pkbf(w0.z,w0.w), pkbf(w1.x,w1.y), pkbf(w1.z,w1.w)};
        *(uint4*)&Ws[sr][sc + 8] = uint4{pkbf(w2.x,w2.y), pkbf(w2.z,w2.w), pkbf(w3.x,w3.y), pkbf(w3.z,w3.w)};
        *(uint4*)&Ds[sr][sc]     = uint4{pkbf(a0.x,a0.y), pkbf(a0.z,a0.w), pkbf(a1.x,a1.y), pkbf(a1.z,a1.w)};
        *(uint4*)&Ds[sr][sc + 8] = uint4{pkbf(a2.x,a2.y), pkbf(a2.z,a2.w), pkbf(a3.x,a3.y), pkbf(a3.z,a3.w)};
        __syncthreads();
        #pragma unroll
        for (int ks = 0; ks < 2; ++ks) {
            const short8 af = *(const short8*)&Ws[wave * 16 + q16][ks * 32 + quad * 8];
            #pragma unroll
            for (int ct = 0; ct < 4; ++ct) {
                const short8 bf = *(const short8*)&Ds[ct * 16 + q16][ks * 32 + quad * 8];
                acc[ct] = __builtin_amdgcn_mfma_f32_16x16x32_bf16(af, bf, acc[ct], 0, 0, 0);
            }
        }
        __syncthreads();
    }

    const int fbase = f0 + wave * 16 + quad * 4;      // 4 consecutive features per lane
    const float4 bb = *(const float4*)(bias + fbase);
    #pragma unroll
    for (int ct = 0; ct < 4; ++ct) {
        int n = m0 + ct * 16 + q16;
        if (n >= MROWS) continue;
        int b  = (n >= BN) ? 1 : 0;
        int nb = n - b * BN;
        float v0 = acc[ct][0] + bb.x, v1 = acc[ct][1] + bb.y;
        float v2 = acc[ct][2] + bb.z, v3 = acc[ct][3] + bb.w;
        if (ROPE) {
            int j0 = (fbase & 31) >> 1;   // even (fbase % 4 == 0); pairs never straddle heads
            const float* fr = (nb < NIMG_) ? (fimg + ((size_t)nb * 16 + j0) * 2)
                                           : (ftxt + ((size_t)(nb - NIMG_) * 16 + j0) * 2);
            float4 cs = *(const float4*)fr;   // c0,s0,c1,s1 (16B-aligned: j0 even)
            float r0 = v0 * cs.x - v1 * cs.y, i0 = v0 * cs.y + v1 * cs.x;
            float r1 = v2 * cs.z - v3 * cs.w, i1 = v2 * cs.w + v3 * cs.z;
            v0 = r0; v1 = i0; v2 = r1; v3 = i1;
        }
        const int h = (fbase >> 5) & 7, hd = fbase & 31;
        if (OMODE == 2) {
            float* op = (float*)outv + (size_t)n * 256 + fbase;
            *(float4*)op = float4{v0, v1, v2, v3};
        } else if (OMODE == 4) {
            unsigned short* op = (unsigned short*)outv + (size_t)(b * HH + h) * 32 * BNP + nb;
            op[(size_t)(hd + 0) * BNP] = f2bs(v0);
            op[(size_t)(hd + 1) * BNP] = f2bs(v1);
            op[(size_t)(hd + 2) * BNP] = f2bs(v2);
            op[(size_t)(hd + 3) * BNP] = f2bs(v3);
        } else {
            const float s = (OMODE == 3) ? QSCALE : 1.f;
            unsigned short* op = (unsigned short*)outv + (((size_t)(b * HH + h) * BN + nb) * 32 + hd);
            *(uint2*)op = uint2{pkbf(v0 * s, v1 * s), pkbf(v2 * s, v3 * s)};
        }
    }
}

// ---------------- MFMA flash attention ----------------
// 4 waves x 16 queries. S^T = K*Q^T; P^T via wave-private LDS; O^T = V^T*P^T.
// Main softmax (oA/LA, keys 0..4047) + separate mem softmax (oB/LB, keys 4048..4111).
// Tile 63 = 16 main + 48 mem keys (split at MFMA granularity); iter 64 = last 16 mem keys.
// Double-buffered K/V staging -> single barrier per iteration. No per-element masks.
__global__ __launch_bounds__(256)
void attn_mfma(const short* __restrict__ Qr, const short* __restrict__ Kr,
               const short* __restrict__ Vt, float* __restrict__ AO)
{
    __shared__ __align__(16) short Ks[2][64][40];   // 80B rows: 16B-aligned, 2-way banks
    __shared__ __align__(16) short Vs[2][32][88];
    __shared__ __align__(16) short Ps[4][16][88];   // wave-private P rows

    const int t    = threadIdx.x;
    const int wave = t >> 6, lane = t & 63, q16 = lane & 15, quad = lane >> 4;
    const int bh = blockIdx.y;
    const int q  = blockIdx.x * 64 + wave * 16 + q16;
    const int qc = (q < BN) ? q : (BN - 1);
    const short8 qf = *(const short8*)(Qr + ((size_t)bh * BN + qc) * 32 + quad * 8);

    f32x4 oA0 = {0,0,0,0}, oA1 = {0,0,0,0}, oB0 = {0,0,0,0}, oB1 = {0,0,0,0};
    float LA = 0.f, LB = 0.f;

    const int kr = t >> 2, kc = t & 3;
    const int vr = t >> 3, vc = t & 7;
    const short* kg = Kr + (size_t)bh * BN * 32 + (size_t)kr * 32 + kc * 8;
    const short* vg = Vt + (size_t)bh * 32 * BNP + (size_t)vr * BNP + vc * 8;
    short* PsW = &Ps[wave][q16][0];

    for (int it = 0; it < 65; ++it) {
        const int buf = it & 1;
        *(uint4*)&Ks[buf][kr][kc * 8] = *(const uint4*)(kg + (size_t)it * 2048);
        *(uint4*)&Vs[buf][vr][vc * 8] = *(const uint4*)(vg + it * 64);
        __syncthreads();

        const short8 v00 = *(const short8*)&Vs[buf][q16][quad * 8];
        const short8 v01 = *(const short8*)&Vs[buf][q16][32 + quad * 8];
        const short8 v10 = *(const short8*)&Vs[buf][16 + q16][quad * 8];
        const short8 v11 = *(const short8*)&Vs[buf][16 + q16][32 + quad * 8];

        if (it < 63) {                      // 64 main keys
            float lsum = 0.f;
            #pragma unroll
            for (int mt = 0; mt < 4; ++mt) {
                const short8 kf = *(const short8*)&Ks[buf][mt * 16 + q16][quad * 8];
                f32x4 z = {0,0,0,0};
                f32x4 s = __builtin_amdgcn_mfma_f32_16x16x32_bf16(kf, qf, z, 0, 0, 0);
                float p0 = fexp2(s[0]), p1 = fexp2(s[1]), p2 = fexp2(s[2]), p3 = fexp2(s[3]);
                lsum += (p0 + p1) + (p2 + p3);
                *(uint2*)(PsW + mt * 16 + quad * 4) = uint2{pkbf(p0, p1), pkbf(p2, p3)};
            }
            LA += lsum;
            const short8 p0 = *(const short8*)(PsW + quad * 8);
            const short8 p1 = *(const short8*)(PsW + 32 + quad * 8);
            oA0 = __builtin_amdgcn_mfma_f32_16x16x32_bf16(v00, p0, oA0, 0, 0, 0);
            oA0 = __builtin_amdgcn_mfma_f32_16x16x32_bf16(v01, p1, oA0, 0, 0, 0);
            oA1 = __builtin_amdgcn_mfma_f32_16x16x32_bf16(v10, p0, oA1, 0, 0, 0);
            oA1 = __builtin_amdgcn_mfma_f32_16x16x32_bf16(v11, p1, oA1, 0, 0, 0);
        } else if (it == 63) {              // 16 main (mt0) + 48 mem (mt1..3)
            {   // variant A: P = [p(mt0), 0] -> oA (keys 0..31 only)
                const short8 kf = *(const short8*)&Ks[buf][q16][quad * 8];
                f32x4 z = {0,0,0,0};
                f32x4 s = __builtin_amdgcn_mfma_f32_16x16x32_bf16(kf, qf, z, 0, 0, 0);
                float p0 = fexp2(s[0]), p1 = fexp2(s[1]), p2 = fexp2(s[2]), p3 = fexp2(s[3]);
                LA += (p0 + p1) + (p2 + p3);
                *(uint2*)(PsW + quad * 4)      = uint2{pkbf(p0, p1), pkbf(p2, p3)};
                *(uint2*)(PsW + 16 + quad * 4) = uint2{0u, 0u};
                const short8 pA = *(const short8*)(PsW + quad * 8);
                oA0 = __builtin_amdgcn_mfma_f32_16x16x32_bf16(v00, pA, oA0, 0, 0, 0);
                oA1 = __builtin_amdgcn_mfma_f32_16x16x32_bf16(v10, pA, oA1, 0, 0, 0);
            }
            {   // variant B: P = [0, p(mt1..3)] -> oB
                float lsum = 0.f;
                *(uint2*)(PsW + quad * 4) = uint2{0u, 0u};
                #pragma unroll
                for (int mt = 1; mt < 4; ++mt) {
                    const short8 kf = *(const short8*)&Ks[buf][mt * 16 + q16][quad * 8];
                    f32x4 z = {0,0,0,0};
                    f32x4 s = __builtin_amdgcn_mfma_f32_16x16x32_bf16(kf, qf, z, 0, 0, 0);
                    float p0 = fexp2(s[0]), p1 = fexp2(s[1]), p2 = fexp2(s[2]), p3 = fexp2(s[3]);
                    lsum += (p0 + p1) + (p2 + p3);
                    *(uint2*)(PsW + mt * 16 + quad * 4) = uint2{pkbf(p0, p1), pkbf(p2, p3)};
                }
                LB += lsum;
                const short8 p0 = *(const short8*)(PsW + quad * 8);
                const short8 p1 = *(const short8*)(PsW + 32 + quad * 8);
                oB0 = __builtin_amdgcn_mfma_f32_16x16x32_bf16(v00, p0, oB0, 0, 0, 0);
                oB0 = __builtin_amdgcn_mfma_f32_16x16x32_bf16(v01, p1, oB0, 0, 0, 0);
                oB1 = __builtin_amdgcn_mfma_f32_16x16x32_bf16(v10, p0, oB1, 0, 0, 0);
                oB1 = __builtin_amdgcn_mfma_f32_16x16x32_bf16(v11, p1, oB1, 0, 0, 0);
            }
        } else {                            // it == 64: last 16 mem keys (mt0)
            const short8 kf = *(const short8*)&Ks[buf][q16][quad * 8];
            f32x4 z = {0,0,0,0};
            f32x4 s = __builtin_amdgcn_mfma_f32_16x16x32_bf16(kf, qf, z, 0, 0, 0);
            float p0 = fexp2(s[0]), p1 = fexp2(s[1]), p2 = fexp2(s[2]), p3 = fexp2(s[3]);
            LB += (p0 + p1) + (p2 + p3);
            *(uint2*)(PsW + quad * 4)      = uint2{pkbf(p0, p1), pkbf(p2, p3)};
            *(uint2*)(PsW + 16 + quad * 4) = uint2{0u, 0u};
            const short8 pB = *(const short8*)(PsW + quad * 8);
            oB0 = __builtin_amdgcn_mfma_f32_16x16x32_bf16(v00, pB, oB0, 0, 0, 0);
            oB1 = __builtin_amdgcn_mfma_f32_16x16x32_bf16(v10, pB, oB1, 0, 0, 0);
        }
    }

    LA += __shfl_xor(LA, 16); LA += __shfl_xor(LA, 32);
    LB += __shfl_xor(LB, 16); LB += __shfl_xor(LB, 32);

    if (q < BN) {
        const float iA = 1.f / LA, iB = 1.f / LB;
        const int b = bh >> 3, h = bh & 7;
        float* ap = AO + ((size_t)b * BN + q) * 256 + h * 32;
        f32x4 w0, w1;
        #pragma unroll
        for (int r = 0; r < 4; ++r) {
            w0[r] = oA0[r] * iA + oB0[r] * iB;
            w1[r] = oA1[r] * iA + oB1[r] * iB;
        }
        *(f32x4*)(ap + quad * 4)      = w0;
        *(f32x4*)(ap + 16 + quad * 4) = w1;
    }
}

extern "C" void kernel_launch(void* const* d_in, const int* in_sizes, int n_in,
                              void* d_out, int out_size, void* d_ws, size_t ws_size,
                              hipStream_t stream)
{
    (void)in_sizes; (void)n_in; (void)out_size; (void)ws_size;
    const float* q    = (const float*)d_in[0];
    const float* k    = (const float*)d_in[1];
    const float* v    = (const float*)d_in[2];
    const float* fimg = (const float*)d_in[3];
    const float* ftxt = (const float*)d_in[4];
    const float* Wq   = (const float*)d_in[5];
    const float* bq   = (const float*)d_in[6];
    const float* Wk   = (const float*)d_in[7];
    const float* bk   = (const float*)d_in[8];
    const float* Wv   = (const float*)d_in[9];
    const float* bv   = (const float*)d_in[10];
    const float* Wo   = (const float*)d_in[11];
    const float* bo   = (const float*)d_in[12];
    // d_in[13] = num_k_exclude_rope = 64 (compiled in)

    // workspace: Qr/Kr bf16 [16][BN][32]; Vt bf16 [16][32][BNP]; AO fp32 [BB][BN][256]
    // 4,210,688 + 4,210,688 + 4,259,840 + 8,421,376 = 21,102,592 B (~20.1 MB)
    char* w = (char*)d_ws;
    short* Qr = (short*)(w);
    short* Kr = (short*)(w + 4210688);
    short* Vt = (short*)(w + 8421376);
    float* AO = (float*)(w + 12681216);

    dim3 gg(129, 4);
    gemm_mfma<true,  3><<<gg, 256, 0, stream>>>(q,  Wq, bq, Qr,    fimg, ftxt);
    gemm_mfma<true,  1><<<gg, 256, 0, stream>>>(k,  Wk, bk, Kr,    fimg, ftxt);
    gemm_mfma<false, 4><<<gg, 256, 0, stream>>>(v,  Wv, bv, Vt,    fimg, ftxt);
    attn_mfma<<<dim3(65, 16), 256, 0, stream>>>(Qr, Kr, Vt, AO);
    gemm_mfma<false, 2><<<gg, 256, 0, stream>>>(AO, Wo, bo, d_out, fimg, ftxt);
}

// Round 6
// 238.650 us; speedup vs baseline: 8.6053x; 1.0638x over previous
//
#include <hip/hip_runtime.h>
#include <hip/hip_bf16.h>

#define BN    4112            // sequence length
#define BNP   4160            // padded row stride for V^T
#define BB    2
#define HH    8
#define NIMG_ 4096
#define NKT   4048            // BN - 64 (main keys)
#define MROWS 8224            // BB*BN
// (1/sqrt(32)) * log2(e): folded into Q so attention uses raw v_exp_f32 (2^x)
#define QSCALE 0.25505402f

typedef __attribute__((ext_vector_type(8))) short short8;   // 8 bf16 (4 VGPRs)
typedef __attribute__((ext_vector_type(4))) float f32x4;

__device__ __forceinline__ unsigned short f2bs(float x) { return __bfloat16_as_ushort(__float2bfloat16(x)); }
__device__ __forceinline__ unsigned pkbf(float a, float b) {
    __hip_bfloat162 h = __float22bfloat162_rn(make_float2(a, b));   // v_cvt_pk_bf16_f32
    unsigned u; __builtin_memcpy(&u, &h, 4); return u;
}
__device__ __forceinline__ float fexp2(float x) {
#if __has_builtin(__builtin_amdgcn_exp2f)
    return __builtin_amdgcn_exp2f(x);
#else
    return exp2f(x);
#endif
}

// ---------------- W pre-pack: fp32 [256][256] x4 -> bf16 ----------------
__global__ __launch_bounds__(256)
void pack_w(const float* __restrict__ Wq, const float* __restrict__ Wk,
            const float* __restrict__ Wv, const float* __restrict__ Wo,
            short* __restrict__ Wb)
{
    const float* srcs[4] = {Wq, Wk, Wv, Wo};
    const float* s = srcs[blockIdx.y];
    int i = blockIdx.x * 1024 + threadIdx.x * 4;
    float4 v = *(const float4*)(s + i);
    *(uint2*)(Wb + (size_t)blockIdx.y * 65536 + i) = uint2{pkbf(v.x, v.y), pkbf(v.z, v.w)};
}

// ---------------- MFMA GEMM: out[n][f] = sum_d A[n][d]*W[f][d] + bias[f] ----------------
// blockIdx.x = feature block (4), blockIdx.y = data block (129): consecutive blocks share
// the A data-tile (L2 locality). W pre-packed bf16. Register-prefetched K-loop, 1 barrier/iter.
// OMODE: 1 = head-split bf16 [bh][n][32], 2 = row-major fp32 (d_out), 3 = head-split bf16
// pre-scaled by QSCALE, 4 = V^T [bh][hd][BNP] via LDS transpose + coalesced stores.
template<bool ABF16, bool ROPE, int OMODE>
__global__ __launch_bounds__(256)
void gemm_mfma(const void* __restrict__ Av, const short* __restrict__ Wb,
               const float* __restrict__ bias, void* __restrict__ outv,
               const float* __restrict__ fimg, const float* __restrict__ ftxt)
{
    __shared__ __align__(16) short Ws[2][64][72];   // 144B rows: 16B-aligned
    __shared__ __align__(16) short Ds[2][64][72];
    const int t    = threadIdx.x;
    const int wave = t >> 6, lane = t & 63, q16 = lane & 15, quad = lane >> 4;
    const int f0 = blockIdx.x * 64;      // features
    const int m0 = blockIdx.y * 64;      // data rows
    const int sr = t >> 2, sc = (t & 3) * 16;
    const int arow = m0 + sr;
    const bool aval = arow < MROWS;
    const short* wp  = Wb + (size_t)(f0 + sr) * 256 + sc;
    const float* apf = (const float*)Av + (size_t)(aval ? arow : 0) * 256 + sc;
    const short* apb = (const short*)Av + (size_t)(aval ? arow : 0) * 256 + sc;

    f32x4 acc[4] = {{0,0,0,0},{0,0,0,0},{0,0,0,0},{0,0,0,0}};

    uint4 wr0, wr1, dr0, dr1;
    // stage k0 = 0
    wr0 = *(const uint4*)(wp); wr1 = *(const uint4*)(wp + 8);
    if (ABF16) {
        dr0 = *(const uint4*)(apb); dr1 = *(const uint4*)(apb + 8);
    } else {
        float4 a0 = *(const float4*)(apf),     a1 = *(const float4*)(apf + 4);
        float4 a2 = *(const float4*)(apf + 8), a3 = *(const float4*)(apf + 12);
        dr0 = uint4{pkbf(a0.x,a0.y), pkbf(a0.z,a0.w), pkbf(a1.x,a1.y), pkbf(a1.z,a1.w)};
        dr1 = uint4{pkbf(a2.x,a2.y), pkbf(a2.z,a2.w), pkbf(a3.x,a3.y), pkbf(a3.z,a3.w)};
    }
    *(uint4*)&Ws[0][sr][sc] = wr0; *(uint4*)&Ws[0][sr][sc + 8] = wr1;
    *(uint4*)&Ds[0][sr][sc] = dr0; *(uint4*)&Ds[0][sr][sc + 8] = dr1;
    __syncthreads();

    #pragma unroll
    for (int ki = 0; ki < 4; ++ki) {
        const int buf = ki & 1;
        if (ki < 3) {                         // prefetch next k-tile into regs
            const int k1 = (ki + 1) * 64;
            wr0 = *(const uint4*)(wp + k1); wr1 = *(const uint4*)(wp + k1 + 8);
            if (ABF16) {
                dr0 = *(const uint4*)(apb + k1); dr1 = *(const uint4*)(apb + k1 + 8);
            } else {
                float4 a0 = *(const float4*)(apf + k1),     a1 = *(const float4*)(apf + k1 + 4);
                float4 a2 = *(const float4*)(apf + k1 + 8), a3 = *(const float4*)(apf + k1 + 12);
                dr0 = uint4{pkbf(a0.x,a0.y), pkbf(a0.z,a0.w), pkbf(a1.x,a1.y), pkbf(a1.z,a1.w)};
                dr1 = uint4{pkbf(a2.x,a2.y), pkbf(a2.z,a2.w), pkbf(a3.x,a3.y), pkbf(a3.z,a3.w)};
            }
        }
        #pragma unroll
        for (int ks = 0; ks < 2; ++ks) {
            const short8 af = *(const short8*)&Ws[buf][wave * 16 + q16][ks * 32 + quad * 8];
            #pragma unroll
            for (int ct = 0; ct < 4; ++ct) {
                const short8 bf = *(const short8*)&Ds[buf][ct * 16 + q16][ks * 32 + quad * 8];
                acc[ct] = __builtin_amdgcn_mfma_f32_16x16x32_bf16(af, bf, acc[ct], 0, 0, 0);
            }
        }
        if (ki < 3) {
            *(uint4*)&Ws[buf ^ 1][sr][sc] = wr0; *(uint4*)&Ws[buf ^ 1][sr][sc + 8] = wr1;
            *(uint4*)&Ds[buf ^ 1][sr][sc] = dr0; *(uint4*)&Ds[buf ^ 1][sr][sc + 8] = dr1;
            __syncthreads();
        }
    }

    const int fbase = f0 + wave * 16 + quad * 4;
    const float4 bb = *(const float4*)(bias + fbase);
    float vs[4][4];
    #pragma unroll
    for (int ct = 0; ct < 4; ++ct) {
        int n = m0 + ct * 16 + q16;
        float v0 = acc[ct][0] + bb.x, v1 = acc[ct][1] + bb.y;
        float v2 = acc[ct][2] + bb.z, v3 = acc[ct][3] + bb.w;
        int b  = (n >= BN) ? 1 : 0;
        int nb = n - b * BN;
        if (ROPE) {
            int j0 = (fbase & 31) >> 1;
            const float* fr = (nb < NIMG_) ? (fimg + ((size_t)nb * 16 + j0) * 2)
                                           : (ftxt + ((size_t)(nb - NIMG_) * 16 + j0) * 2);
            float4 cs = *(const float4*)fr;
            float r0 = v0 * cs.x - v1 * cs.y, i0 = v0 * cs.y + v1 * cs.x;
            float r1 = v2 * cs.z - v3 * cs.w, i1 = v2 * cs.w + v3 * cs.z;
            v0 = r0; v1 = i0; v2 = r1; v3 = i1;
        }
        if (OMODE == 4) {
            vs[ct][0] = v0; vs[ct][1] = v1; vs[ct][2] = v2; vs[ct][3] = v3;
            continue;
        }
        if (n >= MROWS) continue;
        const int h = (fbase >> 5) & 7, hd = fbase & 31;
        if (OMODE == 2) {
            float* op = (float*)outv + (size_t)n * 256 + fbase;
            *(float4*)op = float4{v0, v1, v2, v3};
        } else {
            const float s = (OMODE == 3) ? QSCALE : 1.f;
            unsigned short* op = (unsigned short*)outv + (((size_t)(b * HH + h) * BN + nb) * 32 + hd);
            *(uint2*)op = uint2{pkbf(v0 * s, v1 * s), pkbf(v2 * s, v3 * s)};
        }
    }

    if (OMODE == 4) {
        // transpose through LDS: Tr[f_local][n_local], then coalesced 16B stores
        short (*Tr)[72] = Ds[0];          // last compute used buf 1 -> Ds[0] is free
        const int fl = wave * 16 + quad * 4;
        #pragma unroll
        for (int ct = 0; ct < 4; ++ct) {
            const int nl = ct * 16 + q16;
            Tr[fl + 0][nl] = (short)f2bs(vs[ct][0]);
            Tr[fl + 1][nl] = (short)f2bs(vs[ct][1]);
            Tr[fl + 2][nl] = (short)f2bs(vs[ct][2]);
            Tr[fl + 3][nl] = (short)f2bs(vs[ct][3]);
        }
        __syncthreads();
        const int h0 = (f0 >> 5) & 7;
        #pragma unroll
        for (int ii = 0; ii < 2; ++ii) {
            const int r  = ii * 32 + (t >> 3);     // feature row 0..63
            const int c8 = (t & 7) * 8;            // n chunk base
            const int ng = m0 + c8;                // chunk never straddles batch (4112%8==0)
            if (ng < MROWS) {
                uint4 val = *(const uint4*)&Tr[r][c8];
                int b  = (ng >= BN) ? 1 : 0;
                int nb = ng - b * BN;
                int h  = h0 + (r >> 5), hd = r & 31;
                unsigned short* op = (unsigned short*)outv + ((size_t)(b * HH + h) * 32 + hd) * BNP + nb;
                *(uint4*)op = val;
            }
        }
    }
}

// ---------------- MFMA flash attention (register-prefetched staging) ----------------
// 4 waves x 16 queries. S^T = K*Q^T; P^T via wave-private LDS; O^T = V^T*P^T.
// Main softmax (oA/LA, keys 0..4047) + separate mem softmax (oB/LB, keys 4048..4111).
// Tile 63 = 16 main + 48 mem; iter 64 = last 16 mem keys. 1 barrier/iter; K/V tile for
// it+1 is loaded into VGPRs during compute of it, then ds_written to the other buffer.
__global__ __launch_bounds__(256)
void attn_mfma(const short* __restrict__ Qr, const short* __restrict__ Kr,
               const short* __restrict__ Vt, unsigned short* __restrict__ AO)
{
    __shared__ __align__(16) short Ks[2][64][40];
    __shared__ __align__(16) short Vs[2][32][88];
    __shared__ __align__(16) short Ps[4][16][88];

    const int t    = threadIdx.x;
    const int wave = t >> 6, lane = t & 63, q16 = lane & 15, quad = lane >> 4;
    const int bh = blockIdx.y;
    const int q  = blockIdx.x * 64 + wave * 16 + q16;
    const int qc = (q < BN) ? q : (BN - 1);
    const short8 qf = *(const short8*)(Qr + ((size_t)bh * BN + qc) * 32 + quad * 8);

    f32x4 oA0 = {0,0,0,0}, oA1 = {0,0,0,0}, oB0 = {0,0,0,0}, oB1 = {0,0,0,0};
    float LA = 0.f, LB = 0.f;

    const int kr = t >> 2, kc = t & 3;
    const int vr = t >> 3, vc = t & 7;
    const short* kg = Kr + (size_t)bh * BN * 32 + (size_t)kr * 32 + kc * 8;
    const short* vg = Vt + (size_t)bh * 32 * BNP + (size_t)vr * BNP + vc * 8;
    short* PsW = &Ps[wave][q16][0];

    // stage tile 0
    {
        uint4 k0 = *(const uint4*)(kg);
        uint4 v0 = *(const uint4*)(vg);
        *(uint4*)&Ks[0][kr][kc * 8] = k0;
        *(uint4*)&Vs[0][vr][vc * 8] = v0;
    }
    __syncthreads();

    for (int it = 0; it < 65; ++it) {
        const int buf = it & 1;
        uint4 kreg, vreg;
        if (it < 64) {                       // prefetch tile it+1 into regs
            kreg = *(const uint4*)(kg + (size_t)(it + 1) * 2048);
            vreg = *(const uint4*)(vg + (it + 1) * 64);
        }

        const short8 v00 = *(const short8*)&Vs[buf][q16][quad * 8];
        const short8 v01 = *(const short8*)&Vs[buf][q16][32 + quad * 8];
        const short8 v10 = *(const short8*)&Vs[buf][16 + q16][quad * 8];
        const short8 v11 = *(const short8*)&Vs[buf][16 + q16][32 + quad * 8];

        if (it < 63) {                      // 64 main keys
            float lsum = 0.f;
            #pragma unroll
            for (int mt = 0; mt < 4; ++mt) {
                const short8 kf = *(const short8*)&Ks[buf][mt * 16 + q16][quad * 8];
                f32x4 z = {0,0,0,0};
                f32x4 s = __builtin_amdgcn_mfma_f32_16x16x32_bf16(kf, qf, z, 0, 0, 0);
                float p0 = fexp2(s[0]), p1 = fexp2(s[1]), p2 = fexp2(s[2]), p3 = fexp2(s[3]);
                lsum += (p0 + p1) + (p2 + p3);
                *(uint2*)(PsW + mt * 16 + quad * 4) = uint2{pkbf(p0, p1), pkbf(p2, p3)};
            }
            LA += lsum;
            const short8 p0 = *(const short8*)(PsW + quad * 8);
            const short8 p1 = *(const short8*)(PsW + 32 + quad * 8);
            oA0 = __builtin_amdgcn_mfma_f32_16x16x32_bf16(v00, p0, oA0, 0, 0, 0);
            oA0 = __builtin_amdgcn_mfma_f32_16x16x32_bf16(v01, p1, oA0, 0, 0, 0);
            oA1 = __builtin_amdgcn_mfma_f32_16x16x32_bf16(v10, p0, oA1, 0, 0, 0);
            oA1 = __builtin_amdgcn_mfma_f32_16x16x32_bf16(v11, p1, oA1, 0, 0, 0);
        } else if (it == 63) {              // 16 main (mt0) + 48 mem (mt1..3)
            {
                const short8 kf = *(const short8*)&Ks[buf][q16][quad * 8];
                f32x4 z = {0,0,0,0};
                f32x4 s = __builtin_amdgcn_mfma_f32_16x16x32_bf16(kf, qf, z, 0, 0, 0);
                float p0 = fexp2(s[0]), p1 = fexp2(s[1]), p2 = fexp2(s[2]), p3 = fexp2(s[3]);
                LA += (p0 + p1) + (p2 + p3);
                *(uint2*)(PsW + quad * 4)      = uint2{pkbf(p0, p1), pkbf(p2, p3)};
                *(uint2*)(PsW + 16 + quad * 4) = uint2{0u, 0u};
                const short8 pA = *(const short8*)(PsW + quad * 8);
                oA0 = __builtin_amdgcn_mfma_f32_16x16x32_bf16(v00, pA, oA0, 0, 0, 0);
                oA1 = __builtin_amdgcn_mfma_f32_16x16x32_bf16(v10, pA, oA1, 0, 0, 0);
            }
            {
                float lsum = 0.f;
                *(uint2*)(PsW + quad * 4) = uint2{0u, 0u};
                #pragma unroll
                for (int mt = 1; mt < 4; ++mt) {
                    const short8 kf = *(const short8*)&Ks[buf][mt * 16 + q16][quad * 8];
                    f32x4 z = {0,0,0,0};
                    f32x4 s = __builtin_amdgcn_mfma_f32_16x16x32_bf16(kf, qf, z, 0, 0, 0);
                    float p0 = fexp2(s[0]), p1 = fexp2(s[1]), p2 = fexp2(s[2]), p3 = fexp2(s[3]);
                    lsum += (p0 + p1) + (p2 + p3);
                    *(uint2*)(PsW + mt * 16 + quad * 4) = uint2{pkbf(p0, p1), pkbf(p2, p3)};
                }
                LB += lsum;
                const short8 p0 = *(const short8*)(PsW + quad * 8);
                const short8 p1 = *(const short8*)(PsW + 32 + quad * 8);
                oB0 = __builtin_amdgcn_mfma_f32_16x16x32_bf16(v00, p0, oB0, 0, 0, 0);
                oB0 = __builtin_amdgcn_mfma_f32_16x16x32_bf16(v01, p1, oB0, 0, 0, 0);
                oB1 = __builtin_amdgcn_mfma_f32_16x16x32_bf16(v10, p0, oB1, 0, 0, 0);
                oB1 = __builtin_amdgcn_mfma_f32_16x16x32_bf16(v11, p1, oB1, 0, 0, 0);
            }
        } else {                            // it == 64: last 16 mem keys (mt0)
            const short8 kf = *(const short8*)&Ks[buf][q16][quad * 8];
            f32x4 z = {0,0,0,0};
            f32x4 s = __builtin_amdgcn_mfma_f32_16x16x32_bf16(kf, qf, z, 0, 0, 0);
            float p0 = fexp2(s[0]), p1 = fexp2(s[1]), p2 = fexp2(s[2]), p3 = fexp2(s[3]);
            LB += (p0 + p1) + (p2 + p3);
            *(uint2*)(PsW + quad * 4)      = uint2{pkbf(p0, p1), pkbf(p2, p3)};
            *(uint2*)(PsW + 16 + quad * 4) = uint2{0u, 0u};
            const short8 pB = *(const short8*)(PsW + quad * 8);
            oB0 = __builtin_amdgcn_mfma_f32_16x16x32_bf16(v00, pB, oB0, 0, 0, 0);
            oB1 = __builtin_amdgcn_mfma_f32_16x16x32_bf16(v10, pB, oB1, 0, 0, 0);
        }

        if (it < 64) {
            *(uint4*)&Ks[buf ^ 1][kr][kc * 8] = kreg;
            *(uint4*)&Vs[buf ^ 1][vr][vc * 8] = vreg;
            __syncthreads();
        }
    }

    LA += __shfl_xor(LA, 16); LA += __shfl_xor(LA, 32);
    LB += __shfl_xor(LB, 16); LB += __shfl_xor(LB, 32);

    if (q < BN) {
        const float iA = 1.f / LA, iB = 1.f / LB;
        const int b = bh >> 3, h = bh & 7;
        unsigned short* ap = AO + ((size_t)b * BN + q) * 256 + h * 32;
        float w0[4], w1[4];
        #pragma unroll
        for (int r = 0; r < 4; ++r) {
            w0[r] = oA0[r] * iA + oB0[r] * iB;
            w1[r] = oA1[r] * iA + oB1[r] * iB;
        }
        *(uint2*)(ap + quad * 4)      = uint2{pkbf(w0[0], w0[1]), pkbf(w0[2], w0[3])};
        *(uint2*)(ap + 16 + quad * 4) = uint2{pkbf(w1[0], w1[1]), pkbf(w1[2], w1[3])};
    }
}

extern "C" void kernel_launch(void* const* d_in, const int* in_sizes, int n_in,
                              void* d_out, int out_size, void* d_ws, size_t ws_size,
                              hipStream_t stream)
{
    (void)in_sizes; (void)n_in; (void)out_size; (void)ws_size;
    const float* q    = (const float*)d_in[0];
    const float* k    = (const float*)d_in[1];
    const float* v    = (const float*)d_in[2];
    const float* fimg = (const float*)d_in[3];
    const float* ftxt = (const float*)d_in[4];
    const float* Wq   = (const float*)d_in[5];
    const float* bq   = (const float*)d_in[6];
    const float* Wk   = (const float*)d_in[7];
    const float* bk   = (const float*)d_in[8];
    const float* Wv   = (const float*)d_in[9];
    const float* bv   = (const float*)d_in[10];
    const float* Wo   = (const float*)d_in[11];
    const float* bo   = (const float*)d_in[12];
    // d_in[13] = num_k_exclude_rope = 64 (compiled in)

    // workspace: Qr/Kr bf16 [16][BN][32]; Vt bf16 [16][32][BNP]; AO bf16 [BB][BN][256];
    // Wb bf16 [4][256][256]. Total 17,416,192 B (~16.6 MB)
    char* w = (char*)d_ws;
    short*          Qr = (short*)(w);
    short*          Kr = (short*)(w + 4210688);
    short*          Vt = (short*)(w + 8421376);
    unsigned short* AO = (unsigned short*)(w + 12681216);
    short*          Wb = (short*)(w + 16891904);

    pack_w<<<dim3(64, 4), 256, 0, stream>>>(Wq, Wk, Wv, Wo, Wb);

    dim3 gg(4, 129);   // x = feature block, y = data block (consecutive blocks share A tile)
    gemm_mfma<false, true,  3><<<gg, 256, 0, stream>>>(q,  Wb,           bq, Qr,    fimg, ftxt);
    gemm_mfma<false, true,  1><<<gg, 256, 0, stream>>>(k,  Wb + 65536,   bk, Kr,    fimg, ftxt);
    gemm_mfma<false, false, 4><<<gg, 256, 0, stream>>>(v,  Wb + 131072,  bv, Vt,    fimg, ftxt);
    attn_mfma<<<dim3(65, 16), 256, 0, stream>>>(Qr, Kr, Vt, AO);
    gemm_mfma<true,  false, 2><<<gg, 256, 0, stream>>>(AO, Wb + 196608,  bo, d_out, fimg, ftxt);
}

// Round 7
// 234.383 us; speedup vs baseline: 8.7620x; 1.0182x over previous
//
#include <hip/hip_runtime.h>
#include <hip/hip_bf16.h>

#define BN    4112            // sequence length
#define NKR   4160            // padded key rows: 4048 main + 48 zero-pad + 64 mem
#define BNP   4160            // V^T col stride (= NKR)
#define BB    2
#define HH    8
#define NIMG_ 4096
#define NMAIN 4048
#define MROWS 8224            // BB*BN
// (1/sqrt(32)) * log2(e): folded into Q so attention uses raw v_exp_f32 (2^x)
#define QSCALE 0.25505402f

typedef __attribute__((ext_vector_type(8))) short short8;   // 8 bf16 (4 VGPRs)
typedef __attribute__((ext_vector_type(4))) float f32x4;

__device__ __forceinline__ unsigned short f2bs(float x) { return __bfloat16_as_ushort(__float2bfloat16(x)); }
__device__ __forceinline__ unsigned pkbf(float a, float b) {
    __hip_bfloat162 h = __float22bfloat162_rn(make_float2(a, b));   // v_cvt_pk_bf16_f32
    unsigned u; __builtin_memcpy(&u, &h, 4); return u;
}
__device__ __forceinline__ float fexp2(float x) {
#if __has_builtin(__builtin_amdgcn_exp2f)
    return __builtin_amdgcn_exp2f(x);
#else
    return exp2f(x);
#endif
}

// ---------------- fused QKV projection (one launch) ----------------
// out[n][f] = sum_d A[n][d]*W[f][d] + bias[f]; mode = blockIdx.z:
//  0: Q -> RoPE -> head-split bf16 [bh][n][32], pre-scaled by QSCALE
//  1: K -> RoPE -> head-split bf16 [bh][n'][32], n' = n + (n>=4048 ? 48 : 0) (padded rows)
//  2: V -> V^T bf16 [bh][hd][BNP] via LDS transpose, col' remapped like K
// mode 1/2 blocks with x==0 && y<16 also zero-fill the 48 pad rows/cols of their bh.
__global__ __launch_bounds__(256)
void qkv_mfma(const float* __restrict__ Aq, const float* __restrict__ Ak, const float* __restrict__ Av,
              const float* __restrict__ Wq, const float* __restrict__ Wk, const float* __restrict__ Wv,
              const float* __restrict__ bq, const float* __restrict__ bk, const float* __restrict__ bv,
              short* __restrict__ Qr, short* __restrict__ Kr, short* __restrict__ Vt,
              const float* __restrict__ fimg, const float* __restrict__ ftxt)
{
    __shared__ __align__(16) short Ws[2][64][72];   // 144B rows: 16B-aligned, 2-way banks
    __shared__ __align__(16) short Ds[2][64][72];

    const int mode = blockIdx.z;
    const float* A    = (mode == 0) ? Aq : (mode == 1) ? Ak : Av;
    const float* W    = (mode == 0) ? Wq : (mode == 1) ? Wk : Wv;
    const float* bias = (mode == 0) ? bq : (mode == 1) ? bk : bv;

    const int t    = threadIdx.x;
    const int wave = t >> 6, lane = t & 63, q16 = lane & 15, quad = lane >> 4;
    const int f0 = blockIdx.x * 64;      // features
    const int m0 = blockIdx.y * 64;      // data rows
    const int sr = t >> 2, sc = (t & 3) * 16;
    const int arow = m0 + sr;
    const bool aval = arow < MROWS;
    const float* wp = W + (size_t)(f0 + sr) * 256 + sc;
    const float* ap = A + (size_t)(aval ? arow : 0) * 256 + sc;

    f32x4 acc[4] = {{0,0,0,0},{0,0,0,0},{0,0,0,0},{0,0,0,0}};

    uint4 wr0, wr1, dr0, dr1;
    {   // stage k0 = 0 (pack fp32 -> bf16 in regs)
        float4 a0 = *(const float4*)(wp),     a1 = *(const float4*)(wp + 4);
        float4 a2 = *(const float4*)(wp + 8), a3 = *(const float4*)(wp + 12);
        wr0 = uint4{pkbf(a0.x,a0.y), pkbf(a0.z,a0.w), pkbf(a1.x,a1.y), pkbf(a1.z,a1.w)};
        wr1 = uint4{pkbf(a2.x,a2.y), pkbf(a2.z,a2.w), pkbf(a3.x,a3.y), pkbf(a3.z,a3.w)};
        a0 = *(const float4*)(ap);     a1 = *(const float4*)(ap + 4);
        a2 = *(const float4*)(ap + 8); a3 = *(const float4*)(ap + 12);
        dr0 = uint4{pkbf(a0.x,a0.y), pkbf(a0.z,a0.w), pkbf(a1.x,a1.y), pkbf(a1.z,a1.w)};
        dr1 = uint4{pkbf(a2.x,a2.y), pkbf(a2.z,a2.w), pkbf(a3.x,a3.y), pkbf(a3.z,a3.w)};
    }
    *(uint4*)&Ws[0][sr][sc] = wr0; *(uint4*)&Ws[0][sr][sc + 8] = wr1;
    *(uint4*)&Ds[0][sr][sc] = dr0; *(uint4*)&Ds[0][sr][sc + 8] = dr1;
    __syncthreads();

    #pragma unroll
    for (int ki = 0; ki < 4; ++ki) {
        const int buf = ki & 1;
        if (ki < 3) {                         // prefetch next k-tile into regs
            const int k1 = (ki + 1) * 64;
            float4 a0 = *(const float4*)(wp + k1),     a1 = *(const float4*)(wp + k1 + 4);
            float4 a2 = *(const float4*)(wp + k1 + 8), a3 = *(const float4*)(wp + k1 + 12);
            wr0 = uint4{pkbf(a0.x,a0.y), pkbf(a0.z,a0.w), pkbf(a1.x,a1.y), pkbf(a1.z,a1.w)};
            wr1 = uint4{pkbf(a2.x,a2.y), pkbf(a2.z,a2.w), pkbf(a3.x,a3.y), pkbf(a3.z,a3.w)};
            a0 = *(const float4*)(ap + k1);     a1 = *(const float4*)(ap + k1 + 4);
            a2 = *(const float4*)(ap + k1 + 8); a3 = *(const float4*)(ap + k1 + 12);
            dr0 = uint4{pkbf(a0.x,a0.y), pkbf(a0.z,a0.w), pkbf(a1.x,a1.y), pkbf(a1.z,a1.w)};
            dr1 = uint4{pkbf(a2.x,a2.y), pkbf(a2.z,a2.w), pkbf(a3.x,a3.y), pkbf(a3.z,a3.w)};
        }
        #pragma unroll
        for (int ks = 0; ks < 2; ++ks) {
            const short8 af = *(const short8*)&Ws[buf][wave * 16 + q16][ks * 32 + quad * 8];
            #pragma unroll
            for (int ct = 0; ct < 4; ++ct) {
                const short8 bf = *(const short8*)&Ds[buf][ct * 16 + q16][ks * 32 + quad * 8];
                acc[ct] = __builtin_amdgcn_mfma_f32_16x16x32_bf16(af, bf, acc[ct], 0, 0, 0);
            }
        }
        if (ki < 3) {
            *(uint4*)&Ws[buf ^ 1][sr][sc] = wr0; *(uint4*)&Ws[buf ^ 1][sr][sc + 8] = wr1;
            *(uint4*)&Ds[buf ^ 1][sr][sc] = dr0; *(uint4*)&Ds[buf ^ 1][sr][sc + 8] = dr1;
            __syncthreads();
        }
    }

    const int fbase = f0 + wave * 16 + quad * 4;      // 4 consecutive features per lane
    const float4 bb = *(const float4*)(bias + fbase);
    float vs[4][4];
    #pragma unroll
    for (int ct = 0; ct < 4; ++ct) {
        int n = m0 + ct * 16 + q16;
        float v0 = acc[ct][0] + bb.x, v1 = acc[ct][1] + bb.y;
        float v2 = acc[ct][2] + bb.z, v3 = acc[ct][3] + bb.w;
        int b  = (n >= BN) ? 1 : 0;
        int nb = n - b * BN;
        if (mode < 2) {    // RoPE (lane-local pairs)
            int j0 = (fbase & 31) >> 1;
            const float* fr = (nb < NIMG_) ? (fimg + ((size_t)nb * 16 + j0) * 2)
                                           : (ftxt + ((size_t)(nb - NIMG_) * 16 + j0) * 2);
            float4 cs = *(const float4*)fr;
            float r0 = v0 * cs.x - v1 * cs.y, i0 = v0 * cs.y + v1 * cs.x;
            float r1 = v2 * cs.z - v3 * cs.w, i1 = v2 * cs.w + v3 * cs.z;
            v0 = r0; v1 = i0; v2 = r1; v3 = i1;
        }
        if (mode == 2) {
            vs[ct][0] = v0; vs[ct][1] = v1; vs[ct][2] = v2; vs[ct][3] = v3;
            continue;
        }
        if (n >= MROWS) continue;
        const int h = (fbase >> 5) & 7, hd = fbase & 31;
        if (mode == 0) {
            unsigned short* op = (unsigned short*)Qr + (((size_t)(b * HH + h) * BN + nb) * 32 + hd);
            *(uint2*)op = uint2{pkbf(v0 * QSCALE, v1 * QSCALE), pkbf(v2 * QSCALE, v3 * QSCALE)};
        } else {
            int nk = nb + ((nb >= NMAIN) ? 48 : 0);   // padded key row
            unsigned short* op = (unsigned short*)Kr + (((size_t)(b * HH + h) * NKR + nk) * 32 + hd);
            *(uint2*)op = uint2{pkbf(v0, v1), pkbf(v2, v3)};
        }
    }

    if (mode == 2) {
        // transpose through LDS: Tr[f_local][n_local], then coalesced 16B stores
        short (*Tr)[72] = Ds[0];          // last compute used buf 1 -> Ds[0] is free
        const int fl = wave * 16 + quad * 4;
        #pragma unroll
        for (int ct = 0; ct < 4; ++ct) {
            const int nl = ct * 16 + q16;
            Tr[fl + 0][nl] = (short)f2bs(vs[ct][0]);
            Tr[fl + 1][nl] = (short)f2bs(vs[ct][1]);
            Tr[fl + 2][nl] = (short)f2bs(vs[ct][2]);
            Tr[fl + 3][nl] = (short)f2bs(vs[ct][3]);
        }
        __syncthreads();
        const int h0 = (f0 >> 5) & 7;
        #pragma unroll
        for (int ii = 0; ii < 2; ++ii) {
            const int r  = ii * 32 + (t >> 3);     // feature row 0..63
            const int c8 = (t & 7) * 8;            // n chunk base
            const int ng = m0 + c8;                // chunk never straddles batch (4112%8==0)
            if (ng < MROWS) {
                uint4 val = *(const uint4*)&Tr[r][c8];
                int b  = (ng >= BN) ? 1 : 0;
                int nb = ng - b * BN;
                int nk = nb + ((nb >= NMAIN) ? 48 : 0);   // 4048%8==0: uniform per chunk
                int h  = h0 + (r >> 5), hd = r & 31;
                unsigned short* op = (unsigned short*)Vt + ((size_t)(b * HH + h) * 32 + hd) * BNP + nk;
                *(uint4*)op = val;
            }
        }
    }

    // zero-fill pad rows/cols (rows 4048..4095 of Kr, cols 4048..4095 of Vt) per bh
    if (blockIdx.x == 0 && blockIdx.y < 16 && t < 192) {
        const int bh = blockIdx.y;
        if (mode == 1) {
            short* base = Kr + (size_t)bh * NKR * 32 + (size_t)NMAIN * 32;
            *(uint4*)(base + t * 8) = uint4{0u, 0u, 0u, 0u};
        } else if (mode == 2) {
            short* base = Vt + (size_t)bh * 32 * BNP + (size_t)(t / 6) * BNP + NMAIN + (t % 6) * 8;
            *(uint4*)base = uint4{0u, 0u, 0u, 0u};
        }
    }
}

// ---------------- software-pipelined MFMA flash attention ----------------
// 4 waves x 16 queries. Tiles 0..63 = main keys (incl. 48 zero-pads: p=1, V=0 -> LA -= 48),
// tile 64 = mem keys. Per iteration: QK(it+1) -> Ps[(it+1)&1], then PV(it) from Ps[it&1]
// (written a full iteration ago -> no LDS round-trip stall). K/V triple-buffered in LDS,
// staged one tile ahead from regs loaded one iteration earlier. One barrier per iteration.
__global__ __launch_bounds__(256)
void attn_mfma(const short* __restrict__ Qr, const short* __restrict__ Kr,
               const short* __restrict__ Vt, unsigned short* __restrict__ AO)
{
    __shared__ __align__(16) short Ks[3][64][40];     // 80B rows
    __shared__ __align__(16) short Vs[3][32][72];     // 144B rows
    __shared__ __align__(16) short Ps[2][4][16][72];  // double-buffered wave-private P

    const int t    = threadIdx.x;
    const int wave = t >> 6, lane = t & 63, q16 = lane & 15, quad = lane >> 4;
    const int bh = blockIdx.y;
    const int q  = blockIdx.x * 64 + wave * 16 + q16;
    const int qc = (q < BN) ? q : (BN - 1);
    const short8 qf = *(const short8*)(Qr + ((size_t)bh * BN + qc) * 32 + quad * 8);

    f32x4 oA0 = {0,0,0,0}, oA1 = {0,0,0,0}, oB0 = {0,0,0,0}, oB1 = {0,0,0,0};
    float LA = 0.f, LB = 0.f;

    const int kr = t >> 2, kc = t & 3;
    const int vr = t >> 3, vc = t & 7;
    const short* kg = Kr + (size_t)bh * NKR * 32 + (size_t)kr * 32 + kc * 8;
    const short* vg = Vt + (size_t)bh * 32 * BNP + (size_t)vr * BNP + vc * 8;

    auto qk = [&](int buf, int pb) -> float {
        float lsum = 0.f;
        #pragma unroll
        for (int mt = 0; mt < 4; ++mt) {
            const short8 kf = *(const short8*)&Ks[buf][mt * 16 + q16][quad * 8];
            f32x4 z = {0,0,0,0};
            f32x4 s = __builtin_amdgcn_mfma_f32_16x16x32_bf16(kf, qf, z, 0, 0, 0);
            float p0 = fexp2(s[0]), p1 = fexp2(s[1]), p2 = fexp2(s[2]), p3 = fexp2(s[3]);
            lsum += (p0 + p1) + (p2 + p3);
            *(uint2*)&Ps[pb][wave][q16][mt * 16 + quad * 4] = uint2{pkbf(p0, p1), pkbf(p2, p3)};
        }
        return lsum;
    };
    auto pv = [&](int buf, int pb, f32x4& o0, f32x4& o1) {
        const short8 p0  = *(const short8*)&Ps[pb][wave][q16][quad * 8];
        const short8 p1  = *(const short8*)&Ps[pb][wave][q16][32 + quad * 8];
        const short8 v00 = *(const short8*)&Vs[buf][q16][quad * 8];
        const short8 v01 = *(const short8*)&Vs[buf][q16][32 + quad * 8];
        const short8 v10 = *(const short8*)&Vs[buf][16 + q16][quad * 8];
        const short8 v11 = *(const short8*)&Vs[buf][16 + q16][32 + quad * 8];
        o0 = __builtin_amdgcn_mfma_f32_16x16x32_bf16(v00, p0, o0, 0, 0, 0);
        o0 = __builtin_amdgcn_mfma_f32_16x16x32_bf16(v01, p1, o0, 0, 0, 0);
        o1 = __builtin_amdgcn_mfma_f32_16x16x32_bf16(v10, p0, o1, 0, 0, 0);
        o1 = __builtin_amdgcn_mfma_f32_16x16x32_bf16(v11, p1, o1, 0, 0, 0);
    };

    // prologue: stage tiles 0,1; compute P(0); prefetch tile 2
    uint4 kA = *(const uint4*)(kg),        vA = *(const uint4*)(vg);
    *(uint4*)&Ks[0][kr][kc * 8] = kA;  *(uint4*)&Vs[0][vr][vc * 8] = vA;
    __syncthreads();
    kA = *(const uint4*)(kg + 2048);   vA = *(const uint4*)(vg + 64);
    LA += qk(0, 0);
    *(uint4*)&Ks[1][kr][kc * 8] = kA;  *(uint4*)&Vs[1][vr][vc * 8] = vA;
    __syncthreads();
    kA = *(const uint4*)(kg + 2 * 2048); vA = *(const uint4*)(vg + 2 * 64);

    int bc = 0, bn = 1, bp = 2, pc = 0;   // bufs of tiles it, it+1, it+2; Ps parity of it
    for (int it = 0; it < 64; ++it) {
        uint4 kN, vN;
        const bool pre = (it + 3) <= 64;
        if (pre) { kN = *(const uint4*)(kg + (size_t)(it + 3) * 2048);
                   vN = *(const uint4*)(vg + (it + 3) * 64); }
        float ls = qk(bn, pc ^ 1);                 // QK(it+1) -> Ps[other]
        if (it < 63) LA += ls; else LB += ls;      // tile 64 = mem
        pv(bc, pc, oA0, oA1);                      // PV(it), P written last iter
        if (it + 2 <= 64) { *(uint4*)&Ks[bp][kr][kc * 8] = kA;
                            *(uint4*)&Vs[bp][vr][vc * 8] = vA; }
        if (pre) { kA = kN; vA = vN; }
        __syncthreads();
        int tmp = bc; bc = bn; bn = bp; bp = tmp; pc ^= 1;
    }
    pv(bc, pc, oB0, oB1);                          // PV(64): mem tile

    LA += __shfl_xor(LA, 16); LA += __shfl_xor(LA, 32);
    LB += __shfl_xor(LB, 16); LB += __shfl_xor(LB, 32);
    LA -= 48.f;                                    // 48 zero-pad keys contributed p=1 each

    if (q < BN) {
        const float iA = 1.f / LA, iB = 1.f / LB;
        const int b = bh >> 3, h = bh & 7;
        unsigned short* ap = AO + ((size_t)b * BN + q) * 256 + h * 32;
        float w0[4], w1[4];
        #pragma unroll
        for (int r = 0; r < 4; ++r) {
            w0[r] = oA0[r] * iA + oB0[r] * iB;
            w1[r] = oA1[r] * iA + oB1[r] * iB;
        }
        *(uint2*)(ap + quad * 4)      = uint2{pkbf(w0[0], w0[1]), pkbf(w0[2], w0[3])};
        *(uint2*)(ap + 16 + quad * 4) = uint2{pkbf(w1[0], w1[1]), pkbf(w1[2], w1[3])};
    }
}

// ---------------- output GEMM: d_out[n][f] = AO[n][:] . Wo[f][:] + bo[f] ----------------
__global__ __launch_bounds__(256)
void gemm_out(const unsigned short* __restrict__ A, const float* __restrict__ W,
              const float* __restrict__ bias, float* __restrict__ out)
{
    __shared__ __align__(16) short Ws[2][64][72];
    __shared__ __align__(16) short Ds[2][64][72];
    const int t    = threadIdx.x;
    const int wave = t >> 6, lane = t & 63, q16 = lane & 15, quad = lane >> 4;
    const int f0 = blockIdx.x * 64, m0 = blockIdx.y * 64;
    const int sr = t >> 2, sc = (t & 3) * 16;
    const int arow = m0 + sr;
    const bool aval = arow < MROWS;
    const float* wp = W + (size_t)(f0 + sr) * 256 + sc;
    const unsigned short* ap = A + (size_t)(aval ? arow : 0) * 256 + sc;

    f32x4 acc[4] = {{0,0,0,0},{0,0,0,0},{0,0,0,0},{0,0,0,0}};

    uint4 wr0, wr1, dr0, dr1;
    {
        float4 a0 = *(const float4*)(wp),     a1 = *(const float4*)(wp + 4);
        float4 a2 = *(const float4*)(wp + 8), a3 = *(const float4*)(wp + 12);
        wr0 = uint4{pkbf(a0.x,a0.y), pkbf(a0.z,a0.w), pkbf(a1.x,a1.y), pkbf(a1.z,a1.w)};
        wr1 = uint4{pkbf(a2.x,a2.y), pkbf(a2.z,a2.w), pkbf(a3.x,a3.y), pkbf(a3.z,a3.w)};
        dr0 = *(const uint4*)(ap); dr1 = *(const uint4*)(ap + 8);
    }
    *(uint4*)&Ws[0][sr][sc] = wr0; *(uint4*)&Ws[0][sr][sc + 8] = wr1;
    *(uint4*)&Ds[0][sr][sc] = dr0; *(uint4*)&Ds[0][sr][sc + 8] = dr1;
    __syncthreads();

    #pragma unroll
    for (int ki = 0; ki < 4; ++ki) {
        const int buf = ki & 1;
        if (ki < 3) {
            const int k1 = (ki + 1) * 64;
            float4 a0 = *(const float4*)(wp + k1),     a1 = *(const float4*)(wp + k1 + 4);
            float4 a2 = *(const float4*)(wp + k1 + 8), a3 = *(const float4*)(wp + k1 + 12);
            wr0 = uint4{pkbf(a0.x,a0.y), pkbf(a0.z,a0.w), pkbf(a1.x,a1.y), pkbf(a1.z,a1.w)};
            wr1 = uint4{pkbf(a2.x,a2.y), pkbf(a2.z,a2.w), pkbf(a3.x,a3.y), pkbf(a3.z,a3.w)};
            dr0 = *(const uint4*)(ap + k1); dr1 = *(const uint4*)(ap + k1 + 8);
        }
        #pragma unroll
        for (int ks = 0; ks < 2; ++ks) {
            const short8 af = *(const short8*)&Ws[buf][wave * 16 + q16][ks * 32 + quad * 8];
            #pragma unroll
            for (int ct = 0; ct < 4; ++ct) {
                const short8 bf = *(const short8*)&Ds[buf][ct * 16 + q16][ks * 32 + quad * 8];
                acc[ct] = __builtin_amdgcn_mfma_f32_16x16x32_bf16(af, bf, acc[ct], 0, 0, 0);
            }
        }
        if (ki < 3) {
            *(uint4*)&Ws[buf ^ 1][sr][sc] = wr0; *(uint4*)&Ws[buf ^ 1][sr][sc + 8] = wr1;
            *(uint4*)&Ds[buf ^ 1][sr][sc] = dr0; *(uint4*)&Ds[buf ^ 1][sr][sc + 8] = dr1;
            __syncthreads();
        }
    }

    const int fbase = f0 + wave * 16 + quad * 4;
    const float4 bb = *(const float4*)(bias + fbase);
    #pragma unroll
    for (int ct = 0; ct < 4; ++ct) {
        int n = m0 + ct * 16 + q16;
        if (n >= MROWS) continue;
        float* op = out + (size_t)n * 256 + fbase;
        *(float4*)op = float4{acc[ct][0] + bb.x, acc[ct][1] + bb.y,
                              acc[ct][2] + bb.z, acc[ct][3] + bb.w};
    }
}

extern "C" void kernel_launch(void* const* d_in, const int* in_sizes, int n_in,
                              void* d_out, int out_size, void* d_ws, size_t ws_size,
                              hipStream_t stream)
{
    (void)in_sizes; (void)n_in; (void)out_size; (void)ws_size;
    const float* q    = (const float*)d_in[0];
    const float* k    = (const float*)d_in[1];
    const float* v    = (const float*)d_in[2];
    const float* fimg = (const float*)d_in[3];
    const float* ftxt = (const float*)d_in[4];
    const float* Wq   = (const float*)d_in[5];
    const float* bq   = (const float*)d_in[6];
    const float* Wk   = (const float*)d_in[7];
    const float* bk   = (const float*)d_in[8];
    const float* Wv   = (const float*)d_in[9];
    const float* bv   = (const float*)d_in[10];
    const float* Wo   = (const float*)d_in[11];
    const float* bo   = (const float*)d_in[12];
    // d_in[13] = num_k_exclude_rope = 64 (compiled in)

    // workspace: Qr bf16 [16][BN][32]; Kr bf16 [16][NKR][32]; Vt bf16 [16][32][BNP];
    // AO bf16 [BB][BN][256]. Total 16,941,056 B (~16.2 MB)
    char* w = (char*)d_ws;
    short*          Qr = (short*)(w);                    //  4,210,688
    short*          Kr = (short*)(w + 4210688);          //  4,259,840
    short*          Vt = (short*)(w + 8470528);          //  4,259,840
    unsigned short* AO = (unsigned short*)(w + 12730368);//  4,210,688

    qkv_mfma<<<dim3(4, 129, 3), 256, 0, stream>>>(q, k, v, Wq, Wk, Wv, bq, bk, bv,
                                                  Qr, Kr, Vt, fimg, ftxt);
    attn_mfma<<<dim3(65, 16), 256, 0, stream>>>(Qr, Kr, Vt, AO);
    gemm_out<<<dim3(4, 129), 256, 0, stream>>>(AO, Wo, bo, (float*)d_out);
}

// Round 8
// 207.501 us; speedup vs baseline: 9.8971x; 1.1296x over previous
//
#include <hip/hip_runtime.h>
#include <hip/hip_bf16.h>

#define BN    4112            // sequence length
#define NKR   4160            // padded key rows: 4048 main + 48 zero-pad + 64 mem
#define BNP   4160            // V^T col stride (= NKR)
#define BB    2
#define HH    8
#define NIMG_ 4096
#define NMAIN 4048
#define MROWS 8224            // BB*BN
// (1/sqrt(32)) * log2(e): folded into Q so attention uses raw v_exp_f32 (2^x)
#define QSCALE 0.25505402f

typedef __attribute__((ext_vector_type(8))) short short8;   // 8 bf16 (4 VGPRs)
typedef __attribute__((ext_vector_type(4))) float f32x4;

__device__ __forceinline__ unsigned short f2bs(float x) { return __bfloat16_as_ushort(__float2bfloat16(x)); }
__device__ __forceinline__ unsigned pkbf(float a, float b) {
    __hip_bfloat162 h = __float22bfloat162_rn(make_float2(a, b));   // v_cvt_pk_bf16_f32
    unsigned u; __builtin_memcpy(&u, &h, 4); return u;
}
__device__ __forceinline__ float fexp2(float x) {
#if __has_builtin(__builtin_amdgcn_exp2f)
    return __builtin_amdgcn_exp2f(x);
#else
    return exp2f(x);
#endif
}

// ---------------- fused QKV projection (one launch) ----------------
// out[n][f] = sum_d A[n][d]*W[f][d] + bias[f]; mode = blockIdx.z:
//  0: Q -> RoPE -> head-split bf16 [bh][n][32], pre-scaled by QSCALE
//  1: K -> RoPE -> head-split bf16 [bh][n'][32], n' = n + (n>=4048 ? 48 : 0) (padded rows)
//  2: V -> V^T bf16 [bh][hd][BNP] via LDS transpose, col' remapped like K
// mode 1/2 blocks with x==0 && y<16 also zero-fill the 48 pad rows/cols of their bh.
__global__ __launch_bounds__(256)
void qkv_mfma(const float* __restrict__ Aq, const float* __restrict__ Ak, const float* __restrict__ Av,
              const float* __restrict__ Wq, const float* __restrict__ Wk, const float* __restrict__ Wv,
              const float* __restrict__ bq, const float* __restrict__ bk, const float* __restrict__ bv,
              short* __restrict__ Qr, short* __restrict__ Kr, short* __restrict__ Vt,
              const float* __restrict__ fimg, const float* __restrict__ ftxt)
{
    __shared__ __align__(16) short Ws[2][64][72];   // 144B rows: 16B-aligned, 2-way banks
    __shared__ __align__(16) short Ds[2][64][72];

    const int mode = blockIdx.z;
    const float* A    = (mode == 0) ? Aq : (mode == 1) ? Ak : Av;
    const float* W    = (mode == 0) ? Wq : (mode == 1) ? Wk : Wv;
    const float* bias = (mode == 0) ? bq : (mode == 1) ? bk : bv;

    const int t    = threadIdx.x;
    const int wave = t >> 6, lane = t & 63, q16 = lane & 15, quad = lane >> 4;
    const int f0 = blockIdx.x * 64;      // features
    const int m0 = blockIdx.y * 64;      // data rows
    const int sr = t >> 2, sc = (t & 3) * 16;
    const int arow = m0 + sr;
    const bool aval = arow < MROWS;
    const float* wp = W + (size_t)(f0 + sr) * 256 + sc;
    const float* ap = A + (size_t)(aval ? arow : 0) * 256 + sc;

    f32x4 acc[4] = {{0,0,0,0},{0,0,0,0},{0,0,0,0},{0,0,0,0}};

    uint4 wr0, wr1, dr0, dr1;
    {   // stage k0 = 0 (pack fp32 -> bf16 in regs)
        float4 a0 = *(const float4*)(wp),     a1 = *(const float4*)(wp + 4);
        float4 a2 = *(const float4*)(wp + 8), a3 = *(const float4*)(wp + 12);
        wr0 = uint4{pkbf(a0.x,a0.y), pkbf(a0.z,a0.w), pkbf(a1.x,a1.y), pkbf(a1.z,a1.w)};
        wr1 = uint4{pkbf(a2.x,a2.y), pkbf(a2.z,a2.w), pkbf(a3.x,a3.y), pkbf(a3.z,a3.w)};
        a0 = *(const float4*)(ap);     a1 = *(const float4*)(ap + 4);
        a2 = *(const float4*)(ap + 8); a3 = *(const float4*)(ap + 12);
        dr0 = uint4{pkbf(a0.x,a0.y), pkbf(a0.z,a0.w), pkbf(a1.x,a1.y), pkbf(a1.z,a1.w)};
        dr1 = uint4{pkbf(a2.x,a2.y), pkbf(a2.z,a2.w), pkbf(a3.x,a3.y), pkbf(a3.z,a3.w)};
    }
    *(uint4*)&Ws[0][sr][sc] = wr0; *(uint4*)&Ws[0][sr][sc + 8] = wr1;
    *(uint4*)&Ds[0][sr][sc] = dr0; *(uint4*)&Ds[0][sr][sc + 8] = dr1;
    __syncthreads();

    #pragma unroll
    for (int ki = 0; ki < 4; ++ki) {
        const int buf = ki & 1;
        if (ki < 3) {                         // prefetch next k-tile into regs
            const int k1 = (ki + 1) * 64;
            float4 a0 = *(const float4*)(wp + k1),     a1 = *(const float4*)(wp + k1 + 4);
            float4 a2 = *(const float4*)(wp + k1 + 8), a3 = *(const float4*)(wp + k1 + 12);
            wr0 = uint4{pkbf(a0.x,a0.y), pkbf(a0.z,a0.w), pkbf(a1.x,a1.y), pkbf(a1.z,a1.w)};
            wr1 = uint4{pkbf(a2.x,a2.y), pkbf(a2.z,a2.w), pkbf(a3.x,a3.y), pkbf(a3.z,a3.w)};
            a0 = *(const float4*)(ap + k1);     a1 = *(const float4*)(ap + k1 + 4);
            a2 = *(const float4*)(ap + k1 + 8); a3 = *(const float4*)(ap + k1 + 12);
            dr0 = uint4{pkbf(a0.x,a0.y), pkbf(a0.z,a0.w), pkbf(a1.x,a1.y), pkbf(a1.z,a1.w)};
            dr1 = uint4{pkbf(a2.x,a2.y), pkbf(a2.z,a2.w), pkbf(a3.x,a3.y), pkbf(a3.z,a3.w)};
        }
        #pragma unroll
        for (int ks = 0; ks < 2; ++ks) {
            const short8 af = *(const short8*)&Ws[buf][wave * 16 + q16][ks * 32 + quad * 8];
            #pragma unroll
            for (int ct = 0; ct < 4; ++ct) {
                const short8 bf = *(const short8*)&Ds[buf][ct * 16 + q16][ks * 32 + quad * 8];
                acc[ct] = __builtin_amdgcn_mfma_f32_16x16x32_bf16(af, bf, acc[ct], 0, 0, 0);
            }
        }
        if (ki < 3) {
            *(uint4*)&Ws[buf ^ 1][sr][sc] = wr0; *(uint4*)&Ws[buf ^ 1][sr][sc + 8] = wr1;
            *(uint4*)&Ds[buf ^ 1][sr][sc] = dr0; *(uint4*)&Ds[buf ^ 1][sr][sc + 8] = dr1;
            __syncthreads();
        }
    }

    const int fbase = f0 + wave * 16 + quad * 4;      // 4 consecutive features per lane
    const float4 bb = *(const float4*)(bias + fbase);
    float vs[4][4];
    #pragma unroll
    for (int ct = 0; ct < 4; ++ct) {
        int n = m0 + ct * 16 + q16;
        float v0 = acc[ct][0] + bb.x, v1 = acc[ct][1] + bb.y;
        float v2 = acc[ct][2] + bb.z, v3 = acc[ct][3] + bb.w;
        int b  = (n >= BN) ? 1 : 0;
        int nb = n - b * BN;
        if (mode < 2) {    // RoPE (lane-local pairs)
            int j0 = (fbase & 31) >> 1;
            const float* fr = (nb < NIMG_) ? (fimg + ((size_t)nb * 16 + j0) * 2)
                                           : (ftxt + ((size_t)(nb - NIMG_) * 16 + j0) * 2);
            float4 cs = *(const float4*)fr;
            float r0 = v0 * cs.x - v1 * cs.y, i0 = v0 * cs.y + v1 * cs.x;
            float r1 = v2 * cs.z - v3 * cs.w, i1 = v2 * cs.w + v3 * cs.z;
            v0 = r0; v1 = i0; v2 = r1; v3 = i1;
        }
        if (mode == 2) {
            vs[ct][0] = v0; vs[ct][1] = v1; vs[ct][2] = v2; vs[ct][3] = v3;
            continue;
        }
        if (n >= MROWS) continue;
        const int h = (fbase >> 5) & 7, hd = fbase & 31;
        if (mode == 0) {
            unsigned short* op = (unsigned short*)Qr + (((size_t)(b * HH + h) * BN + nb) * 32 + hd);
            *(uint2*)op = uint2{pkbf(v0 * QSCALE, v1 * QSCALE), pkbf(v2 * QSCALE, v3 * QSCALE)};
        } else {
            int nk = nb + ((nb >= NMAIN) ? 48 : 0);   // padded key row
            unsigned short* op = (unsigned short*)Kr + (((size_t)(b * HH + h) * NKR + nk) * 32 + hd);
            *(uint2*)op = uint2{pkbf(v0, v1), pkbf(v2, v3)};
        }
    }

    if (mode == 2) {
        // transpose through LDS: Tr[f_local][n_local], then coalesced 16B stores
        short (*Tr)[72] = Ds[0];          // last compute used buf 1 -> Ds[0] is free
        const int fl = wave * 16 + quad * 4;
        #pragma unroll
        for (int ct = 0; ct < 4; ++ct) {
            const int nl = ct * 16 + q16;
            Tr[fl + 0][nl] = (short)f2bs(vs[ct][0]);
            Tr[fl + 1][nl] = (short)f2bs(vs[ct][1]);
            Tr[fl + 2][nl] = (short)f2bs(vs[ct][2]);
            Tr[fl + 3][nl] = (short)f2bs(vs[ct][3]);
        }
        __syncthreads();
        const int h0 = (f0 >> 5) & 7;
        #pragma unroll
        for (int ii = 0; ii < 2; ++ii) {
            const int r  = ii * 32 + (t >> 3);     // feature row 0..63
            const int c8 = (t & 7) * 8;            // n chunk base
            const int ng = m0 + c8;                // chunk never straddles batch (4112%8==0)
            if (ng < MROWS) {
                uint4 val = *(const uint4*)&Tr[r][c8];
                int b  = (ng >= BN) ? 1 : 0;
                int nb = ng - b * BN;
                int nk = nb + ((nb >= NMAIN) ? 48 : 0);   // 4048%8==0: uniform per chunk
                int h  = h0 + (r >> 5), hd = r & 31;
                unsigned short* op = (unsigned short*)Vt + ((size_t)(b * HH + h) * 32 + hd) * BNP + nk;
                *(uint4*)op = val;
            }
        }
    }

    // zero-fill pad rows/cols (rows 4048..4095 of Kr, cols 4048..4095 of Vt) per bh
    if (blockIdx.x == 0 && blockIdx.y < 16 && t < 192) {
        const int bh = blockIdx.y;
        if (mode == 1) {
            short* base = Kr + (size_t)bh * NKR * 32 + (size_t)NMAIN * 32;
            *(uint4*)(base + t * 8) = uint4{0u, 0u, 0u, 0u};
        } else if (mode == 2) {
            short* base = Vt + (size_t)bh * 32 * BNP + (size_t)(t / 6) * BNP + NMAIN + (t % 6) * 8;
            *(uint4*)base = uint4{0u, 0u, 0u, 0u};
        }
    }
}

// ---------------- MFMA flash attention, in-register P (permuted-k PV) ----------------
// 4 waves x 16 queries. S^T = K*Q^T (C: col=q, row key=mt*16+quad*4+r). PV uses k=32 MFMA
// with PERMUTED k-axis: k-slot (quad,j) -> key quad*4+(j&3)+16*(j>>2). Under this map the
// exp'd S regs pack IN-LANE into the PV B-operand (no LDS round-trip, no shuffle), and V's
// A-operand is two ds_read_b64 per chunk. Tiles 0..63 = main keys (48 zero-pads: p=1, V=0
// -> LA -= 48), tile 64 = mem segment. 2-buffered K/V staging, register prefetch,
// ONE barrier per iteration. LDS = 19.4 KB -> ~4 blocks/CU.
__global__ __launch_bounds__(256)
void attn_mfma(const short* __restrict__ Qr, const short* __restrict__ Kr,
               const short* __restrict__ Vt, unsigned short* __restrict__ AO)
{
    __shared__ __align__(16) short Ks[2][64][40];     // 80B rows
    __shared__ __align__(16) short Vs[2][32][72];     // 144B rows

    const int t    = threadIdx.x;
    const int wave = t >> 6, lane = t & 63, q16 = lane & 15, quad = lane >> 4;
    const int bh = blockIdx.y;
    const int q  = blockIdx.x * 64 + wave * 16 + q16;
    const int qc = (q < BN) ? q : (BN - 1);
    const short8 qf = *(const short8*)(Qr + ((size_t)bh * BN + qc) * 32 + quad * 8);

    f32x4 oA0 = {0,0,0,0}, oA1 = {0,0,0,0}, oB0 = {0,0,0,0}, oB1 = {0,0,0,0};
    float LA = 0.f, LB = 0.f;

    const int kr = t >> 2, kc = t & 3;
    const int vr = t >> 3, vc = t & 7;
    const short* kg = Kr + (size_t)bh * NKR * 32 + (size_t)kr * 32 + kc * 8;
    const short* vg = Vt + (size_t)bh * 32 * BNP + (size_t)vr * BNP + vc * 8;

    // compute one 64-key tile from LDS buffer `buf`, accumulating into (o0,o1,L)
    auto tile = [&](int buf, f32x4& o0, f32x4& o1, float& L) {
        float lsum = 0.f;
        #pragma unroll
        for (int g = 0; g < 2; ++g) {            // key chunks of 32 (m-tiles 2g, 2g+1)
            const short8 kf0 = *(const short8*)&Ks[buf][(2*g)     * 16 + q16][quad * 8];
            const short8 kf1 = *(const short8*)&Ks[buf][(2*g + 1) * 16 + q16][quad * 8];
            f32x4 z = {0,0,0,0};
            f32x4 s0 = __builtin_amdgcn_mfma_f32_16x16x32_bf16(kf0, qf, z, 0, 0, 0);
            f32x4 s1 = __builtin_amdgcn_mfma_f32_16x16x32_bf16(kf1, qf, z, 0, 0, 0);
            float p0 = fexp2(s0[0]), p1 = fexp2(s0[1]), p2 = fexp2(s0[2]), p3 = fexp2(s0[3]);
            float p4 = fexp2(s1[0]), p5 = fexp2(s1[1]), p6 = fexp2(s1[2]), p7 = fexp2(s1[3]);
            lsum += ((p0 + p1) + (p2 + p3)) + ((p4 + p5) + (p6 + p7));
            // B-operand under permuted k-map: j0..3 = mt 2g keys quad*4+r, j4..7 = mt 2g+1
            uint4 pbu = uint4{pkbf(p0, p1), pkbf(p2, p3), pkbf(p4, p5), pkbf(p6, p7)};
            short8 pb; __builtin_memcpy(&pb, &pbu, 16);
            // A-operand: V^T with the same k-map: two b64 reads per o-half
            uint2 va0 = uint2{*(const unsigned*)&Vs[buf][q16][g*32 + quad*4],
                              *(const unsigned*)&Vs[buf][q16][g*32 + quad*4 + 2]};
            uint2 va1 = uint2{*(const unsigned*)&Vs[buf][q16][g*32 + 16 + quad*4],
                              *(const unsigned*)&Vs[buf][q16][g*32 + 16 + quad*4 + 2]};
            uint4 vau = uint4{va0.x, va0.y, va1.x, va1.y};
            short8 vf; __builtin_memcpy(&vf, &vau, 16);
            o0 = __builtin_amdgcn_mfma_f32_16x16x32_bf16(vf, pb, o0, 0, 0, 0);
            uint2 vb0 = uint2{*(const unsigned*)&Vs[buf][16 + q16][g*32 + quad*4],
                              *(const unsigned*)&Vs[buf][16 + q16][g*32 + quad*4 + 2]};
            uint2 vb1 = uint2{*(const unsigned*)&Vs[buf][16 + q16][g*32 + 16 + quad*4],
                              *(const unsigned*)&Vs[buf][16 + q16][g*32 + 16 + quad*4 + 2]};
            uint4 vbu = uint4{vb0.x, vb0.y, vb1.x, vb1.y};
            short8 vg2; __builtin_memcpy(&vg2, &vbu, 16);
            o1 = __builtin_amdgcn_mfma_f32_16x16x32_bf16(vg2, pb, o1, 0, 0, 0);
        }
        L += lsum;
    };

    // stage tile 0
    *(uint4*)&Ks[0][kr][kc * 8] = *(const uint4*)(kg);
    *(uint4*)&Vs[0][vr][vc * 8] = *(const uint4*)(vg);
    __syncthreads();

    for (int it = 0; it < 64; ++it) {           // main tiles (incl. zero-pad keys)
        const int buf = it & 1;
        uint4 kreg = *(const uint4*)(kg + (size_t)(it + 1) * 2048);
        uint4 vreg = *(const uint4*)(vg + (it + 1) * 64);
        tile(buf, oA0, oA1, LA);
        *(uint4*)&Ks[buf ^ 1][kr][kc * 8] = kreg;
        *(uint4*)&Vs[buf ^ 1][vr][vc * 8] = vreg;
        __syncthreads();
    }
    tile(0, oB0, oB1, LB);                      // tile 64 = mem segment (buf 64&1=0)

    LA += __shfl_xor(LA, 16); LA += __shfl_xor(LA, 32);
    LB += __shfl_xor(LB, 16); LB += __shfl_xor(LB, 32);
    LA -= 48.f;                                 // 48 zero-pad keys contributed p=1 each

    if (q < BN) {
        const float iA = 1.f / LA, iB = 1.f / LB;
        const int b = bh >> 3, h = bh & 7;
        unsigned short* ap = AO + ((size_t)b * BN + q) * 256 + h * 32;
        float w0[4], w1[4];
        #pragma unroll
        for (int r = 0; r < 4; ++r) {
            w0[r] = oA0[r] * iA + oB0[r] * iB;   // hd = quad*4+r
            w1[r] = oA1[r] * iA + oB1[r] * iB;   // hd = 16+quad*4+r
        }
        *(uint2*)(ap + quad * 4)      = uint2{pkbf(w0[0], w0[1]), pkbf(w0[2], w0[3])};
        *(uint2*)(ap + 16 + quad * 4) = uint2{pkbf(w1[0], w1[1]), pkbf(w1[2], w1[3])};
    }
}

// ---------------- output GEMM: d_out[n][f] = AO[n][:] . Wo[f][:] + bo[f] ----------------
__global__ __launch_bounds__(256)
void gemm_out(const unsigned short* __restrict__ A, const float* __restrict__ W,
              const float* __restrict__ bias, float* __restrict__ out)
{
    __shared__ __align__(16) short Ws[2][64][72];
    __shared__ __align__(16) short Ds[2][64][72];
    const int t    = threadIdx.x;
    const int wave = t >> 6, lane = t & 63, q16 = lane & 15, quad = lane >> 4;
    const int f0 = blockIdx.x * 64, m0 = blockIdx.y * 64;
    const int sr = t >> 2, sc = (t & 3) * 16;
    const int arow = m0 + sr;
    const bool aval = arow < MROWS;
    const float* wp = W + (size_t)(f0 + sr) * 256 + sc;
    const unsigned short* ap = A + (size_t)(aval ? arow : 0) * 256 + sc;

    f32x4 acc[4] = {{0,0,0,0},{0,0,0,0},{0,0,0,0},{0,0,0,0}};

    uint4 wr0, wr1, dr0, dr1;
    {
        float4 a0 = *(const float4*)(wp),     a1 = *(const float4*)(wp + 4);
        float4 a2 = *(const float4*)(wp + 8), a3 = *(const float4*)(wp + 12);
        wr0 = uint4{pkbf(a0.x,a0.y), pkbf(a0.z,a0.w), pkbf(a1.x,a1.y), pkbf(a1.z,a1.w)};
        wr1 = uint4{pkbf(a2.x,a2.y), pkbf(a2.z,a2.w), pkbf(a3.x,a3.y), pkbf(a3.z,a3.w)};
        dr0 = *(const uint4*)(ap); dr1 = *(const uint4*)(ap + 8);
    }
    *(uint4*)&Ws[0][sr][sc] = wr0; *(uint4*)&Ws[0][sr][sc + 8] = wr1;
    *(uint4*)&Ds[0][sr][sc] = dr0; *(uint4*)&Ds[0][sr][sc + 8] = dr1;
    __syncthreads();

    #pragma unroll
    for (int ki = 0; ki < 4; ++ki) {
        const int buf = ki & 1;
        if (ki < 3) {
            const int k1 = (ki + 1) * 64;
            float4 a0 = *(const float4*)(wp + k1),     a1 = *(const float4*)(wp + k1 + 4);
            float4 a2 = *(const float4*)(wp + k1 + 8), a3 = *(const float4*)(wp + k1 + 12);
            wr0 = uint4{pkbf(a0.x,a0.y), pkbf(a0.z,a0.w), pkbf(a1.x,a1.y), pkbf(a1.z,a1.w)};
            wr1 = uint4{pkbf(a2.x,a2.y), pkbf(a2.z,a2.w), pkbf(a3.x,a3.y), pkbf(a3.z,a3.w)};
            dr0 = *(const uint4*)(ap + k1); dr1 = *(const uint4*)(ap + k1 + 8);
        }
        #pragma unroll
        for (int ks = 0; ks < 2; ++ks) {
            const short8 af = *(const short8*)&Ws[buf][wave * 16 + q16][ks * 32 + quad * 8];
            #pragma unroll
            for (int ct = 0; ct < 4; ++ct) {
                const short8 bf = *(const short8*)&Ds[buf][ct * 16 + q16][ks * 32 + quad * 8];
                acc[ct] = __builtin_amdgcn_mfma_f32_16x16x32_bf16(af, bf, acc[ct], 0, 0, 0);
            }
        }
        if (ki < 3) {
            *(uint4*)&Ws[buf ^ 1][sr][sc] = wr0; *(uint4*)&Ws[buf ^ 1][sr][sc + 8] = wr1;
            *(uint4*)&Ds[buf ^ 1][sr][sc] = dr0; *(uint4*)&Ds[buf ^ 1][sr][sc + 8] = dr1;
            __syncthreads();
        }
    }

    const int fbase = f0 + wave * 16 + quad * 4;
    const float4 bb = *(const float4*)(bias + fbase);
    #pragma unroll
    for (int ct = 0; ct < 4; ++ct) {
        int n = m0 + ct * 16 + q16;
        if (n >= MROWS) continue;
        float* op = out + (size_t)n * 256 + fbase;
        *(float4*)op = float4{acc[ct][0] + bb.x, acc[ct][1] + bb.y,
                              acc[ct][2] + bb.z, acc[ct][3] + bb.w};
    }
}

extern "C" void kernel_launch(void* const* d_in, const int* in_sizes, int n_in,
                              void* d_out, int out_size, void* d_ws, size_t ws_size,
                              hipStream_t stream)
{
    (void)in_sizes; (void)n_in; (void)out_size; (void)ws_size;
    const float* q    = (const float*)d_in[0];
    const float* k    = (const float*)d_in[1];
    const float* v    = (const float*)d_in[2];
    const float* fimg = (const float*)d_in[3];
    const float* ftxt = (const float*)d_in[4];
    const float* Wq   = (const float*)d_in[5];
    const float* bq   = (const float*)d_in[6];
    const float* Wk   = (const float*)d_in[7];
    const float* bk   = (const float*)d_in[8];
    const float* Wv   = (const float*)d_in[9];
    const float* bv   = (const float*)d_in[10];
    const float* Wo   = (const float*)d_in[11];
    const float* bo   = (const float*)d_in[12];
    // d_in[13] = num_k_exclude_rope = 64 (compiled in)

    // workspace: Qr bf16 [16][BN][32]; Kr bf16 [16][NKR][32]; Vt bf16 [16][32][BNP];
    // AO bf16 [BB][BN][256]. Total 16,941,056 B (~16.2 MB)
    char* w = (char*)d_ws;
    short*          Qr = (short*)(w);                    //  4,210,688
    short*          Kr = (short*)(w + 4210688);          //  4,259,840
    short*          Vt = (short*)(w + 8470528);          //  4,259,840
    unsigned short* AO = (unsigned short*)(w + 12730368);//  4,210,688

    qkv_mfma<<<dim3(4, 129, 3), 256, 0, stream>>>(q, k, v, Wq, Wk, Wv, bq, bk, bv,
                                                  Qr, Kr, Vt, fimg, ftxt);
    attn_mfma<<<dim3(65, 16), 256, 0, stream>>>(Qr, Kr, Vt, AO);
    gemm_out<<<dim3(4, 129), 256, 0, stream>>>(AO, Wo, bo, (float*)d_out);
}

// Round 9
// 199.590 us; speedup vs baseline: 10.2894x; 1.0396x over previous
//
#include <hip/hip_runtime.h>
#include <hip/hip_bf16.h>

#define BN    4112            // sequence length
#define NKR   4160            // padded key rows: 4048 main + 48 zero-pad + 64 mem
#define BNP   4160            // V^T col stride (= NKR)
#define BB    2
#define HH    8
#define NIMG_ 4096
#define NMAIN 4048
#define MROWS 8224            // BB*BN
// (1/sqrt(32)) * log2(e): folded into Q so attention uses raw v_exp_f32 (2^x)
#define QSCALE 0.25505402f

typedef __attribute__((ext_vector_type(8))) short short8;   // 8 bf16 (4 VGPRs)
typedef __attribute__((ext_vector_type(4))) float f32x4;

__device__ __forceinline__ unsigned short f2bs(float x) { return __bfloat16_as_ushort(__float2bfloat16(x)); }
__device__ __forceinline__ unsigned pkbf(float a, float b) {
    __hip_bfloat162 h = __float22bfloat162_rn(make_float2(a, b));   // v_cvt_pk_bf16_f32
    unsigned u; __builtin_memcpy(&u, &h, 4); return u;
}
__device__ __forceinline__ float fexp2(float x) {
#if __has_builtin(__builtin_amdgcn_exp2f)
    return __builtin_amdgcn_exp2f(x);
#else
    return exp2f(x);
#endif
}

// ---------------- fused QKV projection (one launch) ---------------- (unchanged from R8)
__global__ __launch_bounds__(256)
void qkv_mfma(const float* __restrict__ Aq, const float* __restrict__ Ak, const float* __restrict__ Av,
              const float* __restrict__ Wq, const float* __restrict__ Wk, const float* __restrict__ Wv,
              const float* __restrict__ bq, const float* __restrict__ bk, const float* __restrict__ bv,
              short* __restrict__ Qr, short* __restrict__ Kr, short* __restrict__ Vt,
              const float* __restrict__ fimg, const float* __restrict__ ftxt)
{
    __shared__ __align__(16) short Ws[2][64][72];
    __shared__ __align__(16) short Ds[2][64][72];

    const int mode = blockIdx.z;
    const float* A    = (mode == 0) ? Aq : (mode == 1) ? Ak : Av;
    const float* W    = (mode == 0) ? Wq : (mode == 1) ? Wk : Wv;
    const float* bias = (mode == 0) ? bq : (mode == 1) ? bk : bv;

    const int t    = threadIdx.x;
    const int wave = t >> 6, lane = t & 63, q16 = lane & 15, quad = lane >> 4;
    const int f0 = blockIdx.x * 64;
    const int m0 = blockIdx.y * 64;
    const int sr = t >> 2, sc = (t & 3) * 16;
    const int arow = m0 + sr;
    const bool aval = arow < MROWS;
    const float* wp = W + (size_t)(f0 + sr) * 256 + sc;
    const float* ap = A + (size_t)(aval ? arow : 0) * 256 + sc;

    f32x4 acc[4] = {{0,0,0,0},{0,0,0,0},{0,0,0,0},{0,0,0,0}};

    uint4 wr0, wr1, dr0, dr1;
    {
        float4 a0 = *(const float4*)(wp),     a1 = *(const float4*)(wp + 4);
        float4 a2 = *(const float4*)(wp + 8), a3 = *(const float4*)(wp + 12);
        wr0 = uint4{pkbf(a0.x,a0.y), pkbf(a0.z,a0.w), pkbf(a1.x,a1.y), pkbf(a1.z,a1.w)};
        wr1 = uint4{pkbf(a2.x,a2.y), pkbf(a2.z,a2.w), pkbf(a3.x,a3.y), pkbf(a3.z,a3.w)};
        a0 = *(const float4*)(ap);     a1 = *(const float4*)(ap + 4);
        a2 = *(const float4*)(ap + 8); a3 = *(const float4*)(ap + 12);
        dr0 = uint4{pkbf(a0.x,a0.y), pkbf(a0.z,a0.w), pkbf(a1.x,a1.y), pkbf(a1.z,a1.w)};
        dr1 = uint4{pkbf(a2.x,a2.y), pkbf(a2.z,a2.w), pkbf(a3.x,a3.y), pkbf(a3.z,a3.w)};
    }
    *(uint4*)&Ws[0][sr][sc] = wr0; *(uint4*)&Ws[0][sr][sc + 8] = wr1;
    *(uint4*)&Ds[0][sr][sc] = dr0; *(uint4*)&Ds[0][sr][sc + 8] = dr1;
    __syncthreads();

    #pragma unroll
    for (int ki = 0; ki < 4; ++ki) {
        const int buf = ki & 1;
        if (ki < 3) {
            const int k1 = (ki + 1) * 64;
            float4 a0 = *(const float4*)(wp + k1),     a1 = *(const float4*)(wp + k1 + 4);
            float4 a2 = *(const float4*)(wp + k1 + 8), a3 = *(const float4*)(wp + k1 + 12);
            wr0 = uint4{pkbf(a0.x,a0.y), pkbf(a0.z,a0.w), pkbf(a1.x,a1.y), pkbf(a1.z,a1.w)};
            wr1 = uint4{pkbf(a2.x,a2.y), pkbf(a2.z,a2.w), pkbf(a3.x,a3.y), pkbf(a3.z,a3.w)};
            a0 = *(const float4*)(ap + k1);     a1 = *(const float4*)(ap + k1 + 4);
            a2 = *(const float4*)(ap + k1 + 8); a3 = *(const float4*)(ap + k1 + 12);
            dr0 = uint4{pkbf(a0.x,a0.y), pkbf(a0.z,a0.w), pkbf(a1.x,a1.y), pkbf(a1.z,a1.w)};
            dr1 = uint4{pkbf(a2.x,a2.y), pkbf(a2.z,a2.w), pkbf(a3.x,a3.y), pkbf(a3.z,a3.w)};
        }
        #pragma unroll
        for (int ks = 0; ks < 2; ++ks) {
            const short8 af = *(const short8*)&Ws[buf][wave * 16 + q16][ks * 32 + quad * 8];
            #pragma unroll
            for (int ct = 0; ct < 4; ++ct) {
                const short8 bf = *(const short8*)&Ds[buf][ct * 16 + q16][ks * 32 + quad * 8];
                acc[ct] = __builtin_amdgcn_mfma_f32_16x16x32_bf16(af, bf, acc[ct], 0, 0, 0);
            }
        }
        if (ki < 3) {
            *(uint4*)&Ws[buf ^ 1][sr][sc] = wr0; *(uint4*)&Ws[buf ^ 1][sr][sc + 8] = wr1;
            *(uint4*)&Ds[buf ^ 1][sr][sc] = dr0; *(uint4*)&Ds[buf ^ 1][sr][sc + 8] = dr1;
            __syncthreads();
        }
    }

    const int fbase = f0 + wave * 16 + quad * 4;
    const float4 bb = *(const float4*)(bias + fbase);
    float vs[4][4];
    #pragma unroll
    for (int ct = 0; ct < 4; ++ct) {
        int n = m0 + ct * 16 + q16;
        float v0 = acc[ct][0] + bb.x, v1 = acc[ct][1] + bb.y;
        float v2 = acc[ct][2] + bb.z, v3 = acc[ct][3] + bb.w;
        int b  = (n >= BN) ? 1 : 0;
        int nb = n - b * BN;
        if (mode < 2) {
            int j0 = (fbase & 31) >> 1;
            const float* fr = (nb < NIMG_) ? (fimg + ((size_t)nb * 16 + j0) * 2)
                                           : (ftxt + ((size_t)(nb - NIMG_) * 16 + j0) * 2);
            float4 cs = *(const float4*)fr;
            float r0 = v0 * cs.x - v1 * cs.y, i0 = v0 * cs.y + v1 * cs.x;
            float r1 = v2 * cs.z - v3 * cs.w, i1 = v2 * cs.w + v3 * cs.z;
            v0 = r0; v1 = i0; v2 = r1; v3 = i1;
        }
        if (mode == 2) {
            vs[ct][0] = v0; vs[ct][1] = v1; vs[ct][2] = v2; vs[ct][3] = v3;
            continue;
        }
        if (n >= MROWS) continue;
        const int h = (fbase >> 5) & 7, hd = fbase & 31;
        if (mode == 0) {
            unsigned short* op = (unsigned short*)Qr + (((size_t)(b * HH + h) * BN + nb) * 32 + hd);
            *(uint2*)op = uint2{pkbf(v0 * QSCALE, v1 * QSCALE), pkbf(v2 * QSCALE, v3 * QSCALE)};
        } else {
            int nk = nb + ((nb >= NMAIN) ? 48 : 0);
            unsigned short* op = (unsigned short*)Kr + (((size_t)(b * HH + h) * NKR + nk) * 32 + hd);
            *(uint2*)op = uint2{pkbf(v0, v1), pkbf(v2, v3)};
        }
    }

    if (mode == 2) {
        short (*Tr)[72] = Ds[0];
        const int fl = wave * 16 + quad * 4;
        #pragma unroll
        for (int ct = 0; ct < 4; ++ct) {
            const int nl = ct * 16 + q16;
            Tr[fl + 0][nl] = (short)f2bs(vs[ct][0]);
            Tr[fl + 1][nl] = (short)f2bs(vs[ct][1]);
            Tr[fl + 2][nl] = (short)f2bs(vs[ct][2]);
            Tr[fl + 3][nl] = (short)f2bs(vs[ct][3]);
        }
        __syncthreads();
        const int h0 = (f0 >> 5) & 7;
        #pragma unroll
        for (int ii = 0; ii < 2; ++ii) {
            const int r  = ii * 32 + (t >> 3);
            const int c8 = (t & 7) * 8;
            const int ng = m0 + c8;
            if (ng < MROWS) {
                uint4 val = *(const uint4*)&Tr[r][c8];
                int b  = (ng >= BN) ? 1 : 0;
                int nb = ng - b * BN;
                int nk = nb + ((nb >= NMAIN) ? 48 : 0);
                int h  = h0 + (r >> 5), hd = r & 31;
                unsigned short* op = (unsigned short*)Vt + ((size_t)(b * HH + h) * 32 + hd) * BNP + nk;
                *(uint4*)op = val;
            }
        }
    }

    if (blockIdx.x == 0 && blockIdx.y < 16 && t < 192) {
        const int bh = blockIdx.y;
        if (mode == 1) {
            short* base = Kr + (size_t)bh * NKR * 32 + (size_t)NMAIN * 32;
            *(uint4*)(base + t * 8) = uint4{0u, 0u, 0u, 0u};
        } else if (mode == 2) {
            short* base = Vt + (size_t)bh * 32 * BNP + (size_t)(t / 6) * BNP + NMAIN + (t % 6) * 8;
            *(uint4*)base = uint4{0u, 0u, 0u, 0u};
        }
    }
}

// ---------------- MFMA flash attention: in-register P + intra-block key-split ----------------
// 512 thr = 8 waves = 2 groups x 4 waves. Both groups cover the SAME 64 queries; group 0
// handles key-tiles 0..31, group 1 tiles 32..64 (incl. 48 zero-pads in tile 63 and the mem
// segment tile 64). Each group: own double-buffered K/V LDS, register prefetch, in-register
// P via permuted-k PV (k-slot (quad,j) -> key quad*4+(j&3)+16*(j>>2)). One barrier/iter.
// Merge: group 0 partial (O, L) -> LDS -> group 1 normalizes, adds mem softmax, stores.
__global__ __launch_bounds__(512, 8)
void attn_mfma(const short* __restrict__ Qr, const short* __restrict__ Kr,
               const short* __restrict__ Vt, unsigned short* __restrict__ AO)
{
    __shared__ __align__(16) short Ks[2][2][64][40];   // [group][buf] 20480 B
    __shared__ __align__(16) short Vs[2][2][32][72];   // [group][buf] 18432 B

    const int t    = threadIdx.x;
    const int wave = t >> 6, lane = t & 63, q16 = lane & 15, quad = lane >> 4;
    const int grp  = wave >> 2, w4 = wave & 3;
    const int bh = blockIdx.y;
    const int q  = blockIdx.x * 64 + w4 * 16 + q16;
    const int qc = (q < BN) ? q : (BN - 1);
    const short8 qf = *(const short8*)(Qr + ((size_t)bh * BN + qc) * 32 + quad * 8);

    f32x4 oA0 = {0,0,0,0}, oA1 = {0,0,0,0}, oB0 = {0,0,0,0}, oB1 = {0,0,0,0};
    float LA = 0.f, LB = 0.f;

    const int tg = t & 255;                 // group-local thread id
    const int kr = tg >> 2, kc = tg & 3;
    const int vr = tg >> 3, vc = tg & 7;
    // group g starts at tile 32*g: +65536 shorts in Kr rows, +2048 cols in Vt
    const short* kg = Kr + (size_t)bh * NKR * 32 + (size_t)grp * 65536 + (size_t)kr * 32 + kc * 8;
    const short* vg = Vt + (size_t)bh * 32 * BNP + (size_t)vr * BNP + grp * 2048 + vc * 8;
    const int ntiles = 32 + grp;            // group 0: 32 tiles, group 1: 33 (incl. mem)

    auto tile = [&](int buf, f32x4& o0, f32x4& o1, float& L) {
        float lsum = 0.f;
        #pragma unroll
        for (int g = 0; g < 2; ++g) {
            const short8 kf0 = *(const short8*)&Ks[grp][buf][(2*g)     * 16 + q16][quad * 8];
            const short8 kf1 = *(const short8*)&Ks[grp][buf][(2*g + 1) * 16 + q16][quad * 8];
            f32x4 z = {0,0,0,0};
            f32x4 s0 = __builtin_amdgcn_mfma_f32_16x16x32_bf16(kf0, qf, z, 0, 0, 0);
            f32x4 s1 = __builtin_amdgcn_mfma_f32_16x16x32_bf16(kf1, qf, z, 0, 0, 0);
            float p0 = fexp2(s0[0]), p1 = fexp2(s0[1]), p2 = fexp2(s0[2]), p3 = fexp2(s0[3]);
            float p4 = fexp2(s1[0]), p5 = fexp2(s1[1]), p6 = fexp2(s1[2]), p7 = fexp2(s1[3]);
            lsum += ((p0 + p1) + (p2 + p3)) + ((p4 + p5) + (p6 + p7));
            uint4 pbu = uint4{pkbf(p0, p1), pkbf(p2, p3), pkbf(p4, p5), pkbf(p6, p7)};
            short8 pb; __builtin_memcpy(&pb, &pbu, 16);
            uint4 vau = uint4{*(const unsigned*)&Vs[grp][buf][q16][g*32 + quad*4],
                              *(const unsigned*)&Vs[grp][buf][q16][g*32 + quad*4 + 2],
                              *(const unsigned*)&Vs[grp][buf][q16][g*32 + 16 + quad*4],
                              *(const unsigned*)&Vs[grp][buf][q16][g*32 + 16 + quad*4 + 2]};
            short8 vf; __builtin_memcpy(&vf, &vau, 16);
            o0 = __builtin_amdgcn_mfma_f32_16x16x32_bf16(vf, pb, o0, 0, 0, 0);
            uint4 vbu = uint4{*(const unsigned*)&Vs[grp][buf][16 + q16][g*32 + quad*4],
                              *(const unsigned*)&Vs[grp][buf][16 + q16][g*32 + quad*4 + 2],
                              *(const unsigned*)&Vs[grp][buf][16 + q16][g*32 + 16 + quad*4],
                              *(const unsigned*)&Vs[grp][buf][16 + q16][g*32 + 16 + quad*4 + 2]};
            short8 vb; __builtin_memcpy(&vb, &vbu, 16);
            o1 = __builtin_amdgcn_mfma_f32_16x16x32_bf16(vb, pb, o1, 0, 0, 0);
        }
        L += lsum;
    };

    // stage each group's tile 0
    *(uint4*)&Ks[grp][0][kr][kc * 8] = *(const uint4*)(kg);
    *(uint4*)&Vs[grp][0][vr][vc * 8] = *(const uint4*)(vg);
    __syncthreads();

    for (int it = 0; it < 33; ++it) {       // 33 uniform barriers; group 0 idles at it=32
        const int buf = it & 1;
        uint4 kreg, vreg;
        const bool pre = (it + 1) < ntiles;
        if (pre) {
            kreg = *(const uint4*)(kg + (size_t)(it + 1) * 2048);
            vreg = *(const uint4*)(vg + (it + 1) * 64);
        }
        if (it < ntiles) {
            if (grp == 0) tile(buf, oA0, oA1, LA);
            else if (it < 32) tile(buf, oA0, oA1, LA);   // tiles 32..63 (incl. pads)
            else              tile(buf, oB0, oB1, LB);   // tile 64 = mem segment
        }
        if (pre) {
            *(uint4*)&Ks[grp][buf ^ 1][kr][kc * 8] = kreg;
            *(uint4*)&Vs[grp][buf ^ 1][vr][vc * 8] = vreg;
        }
        __syncthreads();
    }

    LA += __shfl_xor(LA, 16); LA += __shfl_xor(LA, 32);
    LB += __shfl_xor(LB, 16); LB += __shfl_xor(LB, 32);

    // exchange group-0 partials through LDS (reuse Ks; all tile reads are done)
    float* ex = (float*)&Ks[0][0][0][0];    // [w4*64+lane]*12 : oA0[4], oA1[4], LA
    const int slot = (w4 * 64 + lane) * 12;
    if (grp == 0) {
        *(f32x4*)(ex + slot)     = oA0;
        *(f32x4*)(ex + slot + 4) = oA1;
        ex[slot + 8] = LA;
    }
    __syncthreads();

    if (grp == 1 && q < BN) {
        f32x4 a0 = *(const f32x4*)(ex + slot);
        f32x4 a1 = *(const f32x4*)(ex + slot + 4);
        float LT = LA + ex[slot + 8] - 48.f;     // 48 zero-pad keys contributed p=1 each
        const float iA = 1.f / LT, iB = 1.f / LB;
        const int b = bh >> 3, h = bh & 7;
        unsigned short* ap = AO + ((size_t)b * BN + q) * 256 + h * 32;
        float w0[4], w1[4];
        #pragma unroll
        for (int r = 0; r < 4; ++r) {
            w0[r] = (oA0[r] + a0[r]) * iA + oB0[r] * iB;   // hd = quad*4+r
            w1[r] = (oA1[r] + a1[r]) * iA + oB1[r] * iB;   // hd = 16+quad*4+r
        }
        *(uint2*)(ap + quad * 4)      = uint2{pkbf(w0[0], w0[1]), pkbf(w0[2], w0[3])};
        *(uint2*)(ap + 16 + quad * 4) = uint2{pkbf(w1[0], w1[1]), pkbf(w1[2], w1[3])};
    }
}

// ---------------- output GEMM ---------------- (unchanged from R8)
__global__ __launch_bounds__(256)
void gemm_out(const unsigned short* __restrict__ A, const float* __restrict__ W,
              const float* __restrict__ bias, float* __restrict__ out)
{
    __shared__ __align__(16) short Ws[2][64][72];
    __shared__ __align__(16) short Ds[2][64][72];
    const int t    = threadIdx.x;
    const int wave = t >> 6, lane = t & 63, q16 = lane & 15, quad = lane >> 4;
    const int f0 = blockIdx.x * 64, m0 = blockIdx.y * 64;
    const int sr = t >> 2, sc = (t & 3) * 16;
    const int arow = m0 + sr;
    const bool aval = arow < MROWS;
    const float* wp = W + (size_t)(f0 + sr) * 256 + sc;
    const unsigned short* ap = A + (size_t)(aval ? arow : 0) * 256 + sc;

    f32x4 acc[4] = {{0,0,0,0},{0,0,0,0},{0,0,0,0},{0,0,0,0}};

    uint4 wr0, wr1, dr0, dr1;
    {
        float4 a0 = *(const float4*)(wp),     a1 = *(const float4*)(wp + 4);
        float4 a2 = *(const float4*)(wp + 8), a3 = *(const float4*)(wp + 12);
        wr0 = uint4{pkbf(a0.x,a0.y), pkbf(a0.z,a0.w), pkbf(a1.x,a1.y), pkbf(a1.z,a1.w)};
        wr1 = uint4{pkbf(a2.x,a2.y), pkbf(a2.z,a2.w), pkbf(a3.x,a3.y), pkbf(a3.z,a3.w)};
        dr0 = *(const uint4*)(ap); dr1 = *(const uint4*)(ap + 8);
    }
    *(uint4*)&Ws[0][sr][sc] = wr0; *(uint4*)&Ws[0][sr][sc + 8] = wr1;
    *(uint4*)&Ds[0][sr][sc] = dr0; *(uint4*)&Ds[0][sr][sc + 8] = dr1;
    __syncthreads();

    #pragma unroll
    for (int ki = 0; ki < 4; ++ki) {
        const int buf = ki & 1;
        if (ki < 3) {
            const int k1 = (ki + 1) * 64;
            float4 a0 = *(const float4*)(wp + k1),     a1 = *(const float4*)(wp + k1 + 4);
            float4 a2 = *(const float4*)(wp + k1 + 8), a3 = *(const float4*)(wp + k1 + 12);
            wr0 = uint4{pkbf(a0.x,a0.y), pkbf(a0.z,a0.w), pkbf(a1.x,a1.y), pkbf(a1.z,a1.w)};
            wr1 = uint4{pkbf(a2.x,a2.y), pkbf(a2.z,a2.w), pkbf(a3.x,a3.y), pkbf(a3.z,a3.w)};
            dr0 = *(const uint4*)(ap + k1); dr1 = *(const uint4*)(ap + k1 + 8);
        }
        #pragma unroll
        for (int ks = 0; ks < 2; ++ks) {
            const short8 af = *(const short8*)&Ws[buf][wave * 16 + q16][ks * 32 + quad * 8];
            #pragma unroll
            for (int ct = 0; ct < 4; ++ct) {
                const short8 bf = *(const short8*)&Ds[buf][ct * 16 + q16][ks * 32 + quad * 8];
                acc[ct] = __builtin_amdgcn_mfma_f32_16x16x32_bf16(af, bf, acc[ct], 0, 0, 0);
            }
        }
        if (ki < 3) {
            *(uint4*)&Ws[buf ^ 1][sr][sc] = wr0; *(uint4*)&Ws[buf ^ 1][sr][sc + 8] = wr1;
            *(uint4*)&Ds[buf ^ 1][sr][sc] = dr0; *(uint4*)&Ds[buf ^ 1][sr][sc + 8] = dr1;
            __syncthreads();
        }
    }

    const int fbase = f0 + wave * 16 + quad * 4;
    const float4 bb = *(const float4*)(bias + fbase);
    #pragma unroll
    for (int ct = 0; ct < 4; ++ct) {
        int n = m0 + ct * 16 + q16;
        if (n >= MROWS) continue;
        float* op = out + (size_t)n * 256 + fbase;
        *(float4*)op = float4{acc[ct][0] + bb.x, acc[ct][1] + bb.y,
                              acc[ct][2] + bb.z, acc[ct][3] + bb.w};
    }
}

extern "C" void kernel_launch(void* const* d_in, const int* in_sizes, int n_in,
                              void* d_out, int out_size, void* d_ws, size_t ws_size,
                              hipStream_t stream)
{
    (void)in_sizes; (void)n_in; (void)out_size; (void)ws_size;
    const float* q    = (const float*)d_in[0];
    const float* k    = (const float*)d_in[1];
    const float* v    = (const float*)d_in[2];
    const float* fimg = (const float*)d_in[3];
    const float* ftxt = (const float*)d_in[4];
    const float* Wq   = (const float*)d_in[5];
    const float* bq   = (const float*)d_in[6];
    const float* Wk   = (const float*)d_in[7];
    const float* bk   = (const float*)d_in[8];
    const float* Wv   = (const float*)d_in[9];
    const float* bv   = (const float*)d_in[10];
    const float* Wo   = (const float*)d_in[11];
    const float* bo   = (const float*)d_in[12];
    // d_in[13] = num_k_exclude_rope = 64 (compiled in)

    // workspace: Qr bf16 [16][BN][32]; Kr bf16 [16][NKR][32]; Vt bf16 [16][32][BNP];
    // AO bf16 [BB][BN][256]. Total 16,941,056 B (~16.2 MB)
    char* w = (char*)d_ws;
    short*          Qr = (short*)(w);                    //  4,210,688
    short*          Kr = (short*)(w + 4210688);          //  4,259,840
    short*          Vt = (short*)(w + 8470528);          //  4,259,840
    unsigned short* AO = (unsigned short*)(w + 12730368);//  4,210,688

    qkv_mfma<<<dim3(4, 129, 3), 256, 0, stream>>>(q, k, v, Wq, Wk, Wv, bq, bk, bv,
                                                  Qr, Kr, Vt, fimg, ftxt);
    attn_mfma<<<dim3(65, 16), 512, 0, stream>>>(Qr, Kr, Vt, AO);
    gemm_out<<<dim3(4, 129), 256, 0, stream>>>(AO, Wo, bo, (float*)d_out);
}